// Round 5
// baseline (360.896 us; speedup 1.0000x reference)
//
#include <hip/hip_runtime.h>

typedef __bf16 bf16x8 __attribute__((ext_vector_type(8)));
typedef __bf16 bf16x4 __attribute__((ext_vector_type(4)));
typedef float f32x4 __attribute__((ext_vector_type(4)));

typedef const __attribute__((address_space(1))) void* gas_t;
typedef __attribute__((address_space(3))) void* las_t;

static constexpr int DIM = 2048;
static constexpr size_t MAT = (size_t)DIM * DIM;  // 4194304 elements

__device__ __forceinline__ float sigmoidf_(float x) { return 1.f / (1.f + __expf(-x)); }

// ---------------------------------------------------------------------------
// fp32 -> bf16 conversion for X, Wq, Wk, Wv, Wo  (grid: (4096, 5), 256 thr)
// ---------------------------------------------------------------------------
__global__ void cvt_kernel(const float* __restrict__ x, const float* __restrict__ wq,
                           const float* __restrict__ wk, const float* __restrict__ wv,
                           const float* __restrict__ wo, __bf16* __restrict__ dst) {
  const float* s;
  switch (blockIdx.y) {
    case 0: s = x; break;
    case 1: s = wq; break;
    case 2: s = wk; break;
    case 3: s = wv; break;
    default: s = wo; break;
  }
  __bf16* d = dst + (size_t)blockIdx.y * MAT;
  size_t i = ((size_t)blockIdx.x * 256 + threadIdx.x) * 4;
  float4 v = *(const float4*)(s + i);
  bf16x4 ov;
  ov[0] = (__bf16)v.x; ov[1] = (__bf16)v.y; ov[2] = (__bf16)v.z; ov[3] = (__bf16)v.w;
  *(bf16x4*)(d + i) = ov;
}

// ---------------------------------------------------------------------------
// 128x128x32 bf16 GEMM body, 4-deep counted-vmcnt pipeline: C = A*B^T (+bias).
// Why: at 1 block/CU (outproj) the old __syncthreads() vmcnt(0) drain stalls
// every K-step by ~HBM latency (BK=32 compute ~400cy < 900cy miss latency) and
// no co-resident block hides it (R2's dbuf-with-syncthreads null).  T4 fix:
// RAW s_barrier (no compiler drain) + counted s_waitcnt vmcnt(8) keeps tiles
// t+1,t+2 (8 loads/wave) in flight across the barrier -- each tile has ~3
// compute phases (~1200cy) to land.  Per-wave vmcnt FIFO: each stage() = 4
// loads, so vmcnt(8) retires exactly the oldest tile.  Barrier makes every
// wave's wait effective block-wide; overwrite target (t+3)&3 was last read at
// t-1, whose ds_reads were consumed (lgkmcnt before MFMA) pre-barrier. LDS
// 2*32 KiB -> 2 blocks/CU still fits.
// ---------------------------------------------------------------------------
template <bool F32OUT>
__device__ __forceinline__ void gemm128(const __bf16* __restrict__ A, const __bf16* __restrict__ B,
                                        const float* __restrict__ bias, bool bias_row, float scale,
                                        void* __restrict__ Cout, int mtile, int ntile,
                                        __bf16* Asm, __bf16* Bsm) {
  const int t = threadIdx.x, lane = t & 63, w = t >> 6;
  const int wrow = (w >> 1) * 64, wcol = (w & 1) * 64;
  const int rbase = mtile * 128, cbase = ntile * 128;
  f32x4 acc[4][4] = {};

  // stage one 128x32 K-tile of A and B into buffer buf (4 global_load_lds)
  auto stage = [&](int buf, int k0) {
#pragma unroll
    for (int i = 0; i < 2; ++i) {
      const int o = i * 4096 + w * 1024 + lane * 16;  // byte offset in 128x32 bf16 tile
      const int r = o >> 6;                           // row 0..127
      const int ke = (o & 63) >> 1;                   // element offset in row (0,8,16,24)
      __builtin_amdgcn_global_load_lds((gas_t)(A + (size_t)(rbase + r) * DIM + k0 + ke),
                                       (las_t)(Asm + buf * 4096 + (o >> 1)), 16, 0, 0);
      __builtin_amdgcn_global_load_lds((gas_t)(B + (size_t)(cbase + r) * DIM + k0 + ke),
                                       (las_t)(Bsm + buf * 4096 + (o >> 1)), 16, 0, 0);
    }
  };

  stage(0, 0);
  stage(1, 32);
  stage(2, 64);
  int buf = 0;
  for (int k0 = 0; k0 < DIM; k0 += 32) {
    // retire only the oldest tile's 4 loads; keep up to 2 tiles in flight
    if (k0 + 64 < DIM)      asm volatile("s_waitcnt vmcnt(8)" ::: "memory");
    else if (k0 + 32 < DIM) asm volatile("s_waitcnt vmcnt(4)" ::: "memory");
    else                    asm volatile("s_waitcnt vmcnt(0)" ::: "memory");
    __builtin_amdgcn_s_barrier();  // raw: does NOT drain vmcnt (unlike __syncthreads)
    if (k0 + 96 < DIM) {
      int sb = buf + 3; if (sb >= 4) sb -= 4;
      stage(sb, k0 + 96);  // tile t+3 -> lands ~3 phases from now
    }

    bf16x8 af[4], bf[4];
#pragma unroll
    for (int i = 0; i < 4; ++i)
      af[i] = *(const bf16x8*)(Asm + buf * 4096 + (wrow + i * 16 + (lane & 15)) * 32 + (lane >> 4) * 8);
#pragma unroll
    for (int j = 0; j < 4; ++j)
      bf[j] = *(const bf16x8*)(Bsm + buf * 4096 + (wcol + j * 16 + (lane & 15)) * 32 + (lane >> 4) * 8);
#pragma unroll
    for (int i = 0; i < 4; ++i)
#pragma unroll
      for (int j = 0; j < 4; ++j)
        acc[i][j] = __builtin_amdgcn_mfma_f32_16x16x32_bf16(af[i], bf[j], acc[i][j], 0, 0, 0);
    buf = (buf + 1) & 3;
  }

  // epilogue: C/D layout col = lane&15, row = (lane>>4)*4 + r
#pragma unroll
  for (int i = 0; i < 4; ++i)
#pragma unroll
    for (int j = 0; j < 4; ++j)
#pragma unroll
      for (int r = 0; r < 4; ++r) {
        const int row = rbase + wrow + i * 16 + (lane >> 4) * 4 + r;
        const int col = cbase + wcol + j * 16 + (lane & 15);
        float v = acc[i][j][r] + (bias_row ? bias[row] : bias[col]);
        v *= scale;
        if (F32OUT)
          ((float*)Cout)[(size_t)row * DIM + col] = v;
        else
          ((__bf16*)Cout)[(size_t)row * DIM + col] = (__bf16)v;
      }
}

// ---------------------------------------------------------------------------
// Fused QKV projections. grid (48,16): sel = x>>4 picks Q / K / V^T.
// ---------------------------------------------------------------------------
__global__ __launch_bounds__(256, 2) void qkv_kernel(
    const __bf16* __restrict__ Xb, const __bf16* __restrict__ Wqb, const __bf16* __restrict__ Wkb,
    const __bf16* __restrict__ Wvb, const float* __restrict__ bq, const float* __restrict__ bk,
    const float* __restrict__ bv, const float* __restrict__ jgate, __bf16* __restrict__ Qo,
    __bf16* __restrict__ Ko, __bf16* __restrict__ Vto) {
  __shared__ __bf16 Asm[4 * 128 * 32];
  __shared__ __bf16 Bsm[4 * 128 * 32];
  const int sel = blockIdx.x >> 4, nt = blockIdx.x & 15, mt = blockIdx.y;
  const __bf16 *A, *B;
  const float* bias;
  __bf16* C;
  bool brow = false;
  float sc = 1.f;
  if (sel == 0) {
    A = Xb; B = Wqb; bias = bq; C = Qo;
    sc = (1.f - 0.1f * sigmoidf_(jgate[0])) * 0.08838834764831843f;  // 1/sqrt(128)
  } else if (sel == 1) {
    A = Xb; B = Wkb; bias = bk; C = Ko;
  } else {
    A = Wvb; B = Xb; bias = bv; C = Vto; brow = true;
  }
  gemm128<false>(A, B, bias, brow, sc, C, mt, nt, Asm, Bsm);
}

// ---------------------------------------------------------------------------
// Output projection: out = Ab Wo^T + bo  (fp32 out)
// ---------------------------------------------------------------------------
__global__ __launch_bounds__(256, 2) void outproj_kernel(const __bf16* __restrict__ Ab,
                                                         const __bf16* __restrict__ Wob,
                                                         const float* __restrict__ bo,
                                                         float* __restrict__ Cout) {
  __shared__ __bf16 Asm[4 * 128 * 32];
  __shared__ __bf16 Bsm[4 * 128 * 32];
  gemm128<true>(Ab, Wob, bo, false, 1.f, Cout, blockIdx.y, blockIdx.x, Asm, Bsm);
}

// ---------------------------------------------------------------------------
// Flash attention. grid (16 qtiles, 16 heads), 512 threads = 8 waves.
// R5: split-K REVERTED (R4 measured attn+merge 90.9 us vs R1's 88.3 -- the
// doubled occupancy bought only 5%, refuting the occupancy theory; limiter is
// the per-wave VALU/TRANS chain).  Kept from R4: zero-conflict stride-64
// XOR-swizzled Ps.  New: T5 setprio(1) around MFMA clusters (+4-7% measured
// on attn, m191) and EXACT defer-max -- skip the rescale pass (4 exp + 36
// VALU) when no row's new tile-max exceeds the running max (bit-exact: the
// skipped path multiplies by exp(0)=1).
// ---------------------------------------------------------------------------
__global__ __launch_bounds__(512) void attn_kernel(const __bf16* __restrict__ Q,
                                                   const __bf16* __restrict__ Kg,
                                                   const __bf16* __restrict__ VT,
                                                   const float* __restrict__ ogate,
                                                   __bf16* __restrict__ O) {
  __shared__ __bf16 Ks[2][4 * 64 * 32];   // 2 x 16 KiB, layout [c][key][32] (swizzled slots)
  __shared__ __bf16 Vs[2][2 * 128 * 32];  // 2 x 16 KiB, layout [cc][d][32] (swizzled slots)
  __shared__ __bf16 Ps[8 * 16 * 64];      // 16 KiB, stride 64 + XOR swizzle (0 conflicts)
  const int t = threadIdx.x, lane = t & 63, w = t >> 6;
  const int h = blockIdx.y, qt = blockIdx.x;
  const float beta = sigmoidf_(ogate[0]) * 0.05f / 2048.0f;

  // per-lane swizzled 8-elem slot offset for K/V reads:
  // slot' = (lane>>4) ^ (row bits 1..2), row = *16 + (lane&15)
  const int rs8 = (((lane >> 4) ^ ((lane >> 1) & 3)) & 3) * 8;

  const int qrow = qt * 128 + w * 16 + (lane & 15);
  bf16x8 qf[4];
#pragma unroll
  for (int c = 0; c < 4; ++c)
    qf[c] = *(const bf16x8*)(Q + (size_t)qrow * DIM + h * 128 + c * 32 + (lane >> 4) * 8);

  f32x4 oacc[8] = {};
  float m_r[4], l_r[4];
#pragma unroll
  for (int r = 0; r < 4; ++r) { m_r[r] = -1e30f; l_r[r] = 0.f; }

  // stage tile kt into buffer buf (LDS dest linear, global source pre-swizzled)
  auto stage = [&](int buf, int kt) {
#pragma unroll
    for (int i = 0; i < 2; ++i) {
      const int o = i * 8192 + w * 1024 + lane * 16;   // linear LDS byte offset
      const int oz = o ^ (((o >> 7) & 3) << 4);        // swizzled logical address
      const int ke = (oz & 63) >> 1;                   // element offset in 32-wide row
      // K tile: [c][key][32]
      const int c = oz >> 12, key = (oz & 4095) >> 6;
      __builtin_amdgcn_global_load_lds(
          (gas_t)(Kg + (size_t)(kt + key) * DIM + h * 128 + c * 32 + ke),
          (las_t)(&Ks[buf][0] + (o >> 1)), 16, 0, 0);
      // V^T tile: [cc][d][32]
      const int d = (o & 8191) >> 6;
      __builtin_amdgcn_global_load_lds(
          (gas_t)(VT + (size_t)(h * 128 + d) * DIM + kt + i * 32 + ke),
          (las_t)(&Vs[buf][0] + (o >> 1)), 16, 0, 0);
    }
  };

  stage(0, 0);
  int p = 0;
  for (int kt = 0; kt < 2048; kt += 64) {
    __syncthreads();  // buf[p] staged (vmcnt drained here); buf[p^1] reads from t-1 done
    if (kt + 64 < 2048) stage(p ^ 1, kt + 64);  // prefetch next tile; drains at NEXT barrier

    // QK^T: sc[j] = 16q x 16key block j
    __builtin_amdgcn_s_setprio(1);
    f32x4 sc[4];
#pragma unroll
    for (int j = 0; j < 4; ++j) {
      f32x4 a = {};
#pragma unroll
      for (int c = 0; c < 4; ++c) {
        bf16x8 kf = *(const bf16x8*)(&Ks[p][0] + c * 2048 + (j * 16 + (lane & 15)) * 32 + rs8);
        a = __builtin_amdgcn_mfma_f32_16x16x32_bf16(qf[c], kf, a, 0, 0, 0);
      }
      sc[j] = a;
    }
    __builtin_amdgcn_s_setprio(0);
    // per-key position bias
#pragma unroll
    for (int j = 0; j < 4; ++j) {
      const float pb = beta * (float)(kt + j * 16 + (lane & 15));
#pragma unroll
      for (int r = 0; r < 4; ++r) sc[j][r] += pb;
    }
    // row max over 64 keys: regs then 16-lane butterfly
    float rmax[4];
#pragma unroll
    for (int r = 0; r < 4; ++r)
      rmax[r] = fmaxf(fmaxf(sc[0][r], sc[1][r]), fmaxf(sc[2][r], sc[3][r]));
#pragma unroll
    for (int msk = 1; msk < 16; msk <<= 1)
#pragma unroll
      for (int r = 0; r < 4; ++r) rmax[r] = fmaxf(rmax[r], __shfl_xor(rmax[r], msk, 64));

    // defer-max (exact): rescale only if some row's max grew; otherwise the
    // rescale factor is exp(0)=1 and skipping is bit-identical.
    bool need = (rmax[0] > m_r[0]) | (rmax[1] > m_r[1]) |
                (rmax[2] > m_r[2]) | (rmax[3] > m_r[3]);
    if (__any(need)) {
#pragma unroll
      for (int r = 0; r < 4; ++r) {
        const float mn = fmaxf(m_r[r], rmax[r]);
        const float al = __expf(m_r[r] - mn);
        m_r[r] = mn;
        l_r[r] *= al;
#pragma unroll
        for (int d = 0; d < 8; ++d) oacc[d][r] *= al;
      }
    }
#pragma unroll
    for (int j = 0; j < 4; ++j)
#pragma unroll
      for (int r = 0; r < 4; ++r) sc[j][r] = __expf(sc[j][r] - m_r[r]);

    float rs[4];
#pragma unroll
    for (int r = 0; r < 4; ++r) rs[r] = (sc[0][r] + sc[1][r]) + (sc[2][r] + sc[3][r]);
#pragma unroll
    for (int msk = 1; msk < 16; msk <<= 1)
#pragma unroll
      for (int r = 0; r < 4; ++r) rs[r] += __shfl_xor(rs[r], msk, 64);
#pragma unroll
    for (int r = 0; r < 4; ++r) l_r[r] += rs[r];

    // write P: logical [16 q][64 key] per wave, stride 64, elem ^= (q&7)<<3.
    // Wave-private region: same-wave LDS ordering via lgkmcnt, no barrier.
    {
      __bf16* pw = Ps + w * 1024;
#pragma unroll
      for (int j = 0; j < 4; ++j)
#pragma unroll
        for (int r = 0; r < 4; ++r) {
          const int q = (lane >> 4) * 4 + r;
          pw[(q * 64 + j * 16 + (lane & 15)) ^ ((q & 7) << 3)] = (__bf16)sc[j][r];
        }
    }

    // PV: oacc[d] += P(16x64) * V(64 x 16d-block)
    __builtin_amdgcn_s_setprio(1);
#pragma unroll
    for (int cc = 0; cc < 2; ++cc) {
      const int pe = (w * 1024 + (lane & 15) * 64 + cc * 32 + (lane >> 4) * 8) ^ ((lane & 7) << 3);
      bf16x8 pa = *(const bf16x8*)(Ps + pe);
#pragma unroll
      for (int d = 0; d < 8; ++d) {
        bf16x8 vf = *(const bf16x8*)(&Vs[p][0] + cc * 4096 + (d * 16 + (lane & 15)) * 32 + rs8);
        oacc[d] = __builtin_amdgcn_mfma_f32_16x16x32_bf16(pa, vf, oacc[d], 0, 0, 0);
      }
    }
    __builtin_amdgcn_s_setprio(0);
    p ^= 1;
  }

  // epilogue: normalize and store bf16 attention output [S][2048]
#pragma unroll
  for (int d = 0; d < 8; ++d)
#pragma unroll
    for (int r = 0; r < 4; ++r) {
      const int row = qt * 128 + w * 16 + (lane >> 4) * 4 + r;
      const int col = h * 128 + d * 16 + (lane & 15);
      O[(size_t)row * DIM + col] = (__bf16)(oacc[d][r] / l_r[r]);
    }
}

// ---------------------------------------------------------------------------
extern "C" void kernel_launch(void* const* d_in, const int* in_sizes, int n_in,
                              void* d_out, int out_size, void* d_ws, size_t ws_size,
                              hipStream_t stream) {
  const float* X  = (const float*)d_in[0];
  const float* Wq = (const float*)d_in[1];
  const float* bq = (const float*)d_in[2];
  const float* Wk = (const float*)d_in[3];
  const float* bk = (const float*)d_in[4];
  const float* Wv = (const float*)d_in[5];
  const float* bv = (const float*)d_in[6];
  const float* Wo = (const float*)d_in[7];
  const float* bo = (const float*)d_in[8];
  // gates: truth(9), balance(10), order(11), justice(12), harmony(13)
  const float* order_g   = (const float*)d_in[11];
  const float* justice_g = (const float*)d_in[12];

  __bf16* wsb = (__bf16*)d_ws;
  __bf16* Xb  = wsb + 0 * MAT;
  __bf16* Wqb = wsb + 1 * MAT;
  __bf16* Wkb = wsb + 2 * MAT;
  __bf16* Wvb = wsb + 3 * MAT;
  __bf16* Wob = wsb + 4 * MAT;
  __bf16* Qb  = wsb + 5 * MAT;
  __bf16* Kb  = wsb + 6 * MAT;
  __bf16* VTb = wsb + 7 * MAT;
  __bf16* Ab  = Xb;  // alias: X is dead after qkv_kernel (keeps ws use at 64 MB)

  cvt_kernel<<<dim3(4096, 5), 256, 0, stream>>>(X, Wq, Wk, Wv, Wo, wsb);
  qkv_kernel<<<dim3(48, 16), 256, 0, stream>>>(Xb, Wqb, Wkb, Wvb, bq, bk, bv, justice_g,
                                               Qb, Kb, VTb);
  attn_kernel<<<dim3(16, 16), 512, 0, stream>>>(Qb, Kb, VTb, order_g, Ab);
  outproj_kernel<<<dim3(16, 16), 256, 0, stream>>>(Ab, Wob, bo, (float*)d_out);
}

// Round 6
// 321.008 us; speedup vs baseline: 1.1243x; 1.1243x over previous
//
#include <hip/hip_runtime.h>

typedef __bf16 bf16x8 __attribute__((ext_vector_type(8)));
typedef __bf16 bf16x4 __attribute__((ext_vector_type(4)));
typedef float f32x4 __attribute__((ext_vector_type(4)));

typedef const __attribute__((address_space(1))) void* gas_t;
typedef __attribute__((address_space(3))) void* las_t;

static constexpr int DIM = 2048;
static constexpr size_t MAT = (size_t)DIM * DIM;  // 4194304 elements

__device__ __forceinline__ float sigmoidf_(float x) { return 1.f / (1.f + __expf(-x)); }

// ---------------------------------------------------------------------------
// fp32 -> bf16 conversion for X, Wq, Wk, Wv, Wo  (grid: (4096, 5), 256 thr)
// ---------------------------------------------------------------------------
__global__ void cvt_kernel(const float* __restrict__ x, const float* __restrict__ wq,
                           const float* __restrict__ wk, const float* __restrict__ wv,
                           const float* __restrict__ wo, __bf16* __restrict__ dst) {
  const float* s;
  switch (blockIdx.y) {
    case 0: s = x; break;
    case 1: s = wq; break;
    case 2: s = wk; break;
    case 3: s = wv; break;
    default: s = wo; break;
  }
  __bf16* d = dst + (size_t)blockIdx.y * MAT;
  size_t i = ((size_t)blockIdx.x * 256 + threadIdx.x) * 4;
  float4 v = *(const float4*)(s + i);
  bf16x4 ov;
  ov[0] = (__bf16)v.x; ov[1] = (__bf16)v.y; ov[2] = (__bf16)v.z; ov[3] = (__bf16)v.w;
  *(bf16x4*)(d + i) = ov;
}

// ---------------------------------------------------------------------------
// 128xBN x32 bf16 GEMM body: C = A * B^T  (+bias, scale).  R1-form: single
// buffer, 2 barriers/K-step -- measured BEST (R5's counted-vmcnt 4-deep
// pipeline regressed qkv 83->112 us: 64 KiB LDS cut co-residency 3->2/CU and
// the compiler defeats source-level counted vmcnt outside a full 8-phase
// port; m131/m141 reproduced).  BN=128 for qkv (768 blocks, 3/CU); BN=64 for
// outproj (512 blocks, 2/CU -- at BN=128 its 256 blocks were 1/CU with zero
// inter-block overlap, the R5-profile-inferred ~110 us chunk).
// ---------------------------------------------------------------------------
template <bool F32OUT, int BN>
__device__ __forceinline__ void gemm128(const __bf16* __restrict__ A, const __bf16* __restrict__ B,
                                        const float* __restrict__ bias, bool bias_row, float scale,
                                        void* __restrict__ Cout, int mtile, int ntile,
                                        __bf16* Asm, __bf16* Bsm) {
  constexpr int NJ = BN / 32;  // B-fragment blocks per wave (4 or 2)
  const int t = threadIdx.x, lane = t & 63, w = t >> 6;
  const int wrow = (w >> 1) * 64, wcol = (w & 1) * (BN / 2);
  const int rbase = mtile * 128, cbase = ntile * BN;
  f32x4 acc[4][NJ] = {};

  for (int k0 = 0; k0 < DIM; k0 += 32) {
    __syncthreads();  // previous iteration's LDS reads complete
#pragma unroll
    for (int i = 0; i < 2; ++i) {  // A tile: 128 rows x 32 k = 8 KiB
      const int o = i * 4096 + w * 1024 + lane * 16;
      const int r = o >> 6;
      const int ke = (o & 63) >> 1;
      __builtin_amdgcn_global_load_lds((gas_t)(A + (size_t)(rbase + r) * DIM + k0 + ke),
                                       (las_t)(Asm + (o >> 1)), 16, 0, 0);
    }
#pragma unroll
    for (int i = 0; i < BN / 64; ++i) {  // B tile: BN rows x 32 k
      const int o = i * 4096 + w * 1024 + lane * 16;
      const int r = o >> 6;
      const int ke = (o & 63) >> 1;
      __builtin_amdgcn_global_load_lds((gas_t)(B + (size_t)(cbase + r) * DIM + k0 + ke),
                                       (las_t)(Bsm + (o >> 1)), 16, 0, 0);
    }
    __syncthreads();  // compiler drains vmcnt before barrier

    bf16x8 af[4], bf[NJ];
#pragma unroll
    for (int i = 0; i < 4; ++i)
      af[i] = *(const bf16x8*)(Asm + (wrow + i * 16 + (lane & 15)) * 32 + (lane >> 4) * 8);
#pragma unroll
    for (int j = 0; j < NJ; ++j)
      bf[j] = *(const bf16x8*)(Bsm + (wcol + j * 16 + (lane & 15)) * 32 + (lane >> 4) * 8);
#pragma unroll
    for (int i = 0; i < 4; ++i)
#pragma unroll
      for (int j = 0; j < NJ; ++j)
        acc[i][j] = __builtin_amdgcn_mfma_f32_16x16x32_bf16(af[i], bf[j], acc[i][j], 0, 0, 0);
  }

  // epilogue: C/D layout col = lane&15, row = (lane>>4)*4 + r
#pragma unroll
  for (int i = 0; i < 4; ++i)
#pragma unroll
    for (int j = 0; j < NJ; ++j)
#pragma unroll
      for (int r = 0; r < 4; ++r) {
        const int row = rbase + wrow + i * 16 + (lane >> 4) * 4 + r;
        const int col = cbase + wcol + j * 16 + (lane & 15);
        float v = acc[i][j][r] + (bias_row ? bias[row] : bias[col]);
        v *= scale;
        if (F32OUT)
          ((float*)Cout)[(size_t)row * DIM + col] = v;
        else
          ((__bf16*)Cout)[(size_t)row * DIM + col] = (__bf16)v;
      }
}

// ---------------------------------------------------------------------------
// Fused QKV projections. grid (48,16): sel = x>>4 picks Q / K / V^T.
// ---------------------------------------------------------------------------
__global__ __launch_bounds__(256, 2) void qkv_kernel(
    const __bf16* __restrict__ Xb, const __bf16* __restrict__ Wqb, const __bf16* __restrict__ Wkb,
    const __bf16* __restrict__ Wvb, const float* __restrict__ bq, const float* __restrict__ bk,
    const float* __restrict__ bv, const float* __restrict__ jgate, __bf16* __restrict__ Qo,
    __bf16* __restrict__ Ko, __bf16* __restrict__ Vto) {
  __shared__ __bf16 Asm[128 * 32];
  __shared__ __bf16 Bsm[128 * 32];
  const int sel = blockIdx.x >> 4, nt = blockIdx.x & 15, mt = blockIdx.y;
  const __bf16 *A, *B;
  const float* bias;
  __bf16* C;
  bool brow = false;
  float sc = 1.f;
  if (sel == 0) {
    A = Xb; B = Wqb; bias = bq; C = Qo;
    sc = (1.f - 0.1f * sigmoidf_(jgate[0])) * 0.08838834764831843f;  // 1/sqrt(128)
  } else if (sel == 1) {
    A = Xb; B = Wkb; bias = bk; C = Ko;
  } else {
    A = Wvb; B = Xb; bias = bv; C = Vto; brow = true;
  }
  gemm128<false, 128>(A, B, bias, brow, sc, C, mt, nt, Asm, Bsm);
}

// ---------------------------------------------------------------------------
// Output projection: out = Ab Wo^T + bo  (fp32 out).  128x64 tiles ->
// grid (32,16) = 512 blocks = 2/CU for inter-block latency overlap.
// ---------------------------------------------------------------------------
__global__ __launch_bounds__(256, 2) void outproj_kernel(const __bf16* __restrict__ Ab,
                                                         const __bf16* __restrict__ Wob,
                                                         const float* __restrict__ bo,
                                                         float* __restrict__ Cout) {
  __shared__ __bf16 Asm[128 * 32];
  __shared__ __bf16 Bsm[64 * 32];
  gemm128<true, 64>(Ab, Wob, bo, false, 1.f, Cout, blockIdx.y, blockIdx.x, Asm, Bsm);
}

// ---------------------------------------------------------------------------
// Flash attention. grid (16 qtiles, 16 heads), 512 threads = 8 waves.
// R5 form kept: zero-conflict stride-64 XOR Ps, T5 setprio around MFMA
// clusters, exact defer-max (skip rescale when no row max grew).
// ---------------------------------------------------------------------------
__global__ __launch_bounds__(512) void attn_kernel(const __bf16* __restrict__ Q,
                                                   const __bf16* __restrict__ Kg,
                                                   const __bf16* __restrict__ VT,
                                                   const float* __restrict__ ogate,
                                                   __bf16* __restrict__ O) {
  __shared__ __bf16 Ks[2][4 * 64 * 32];   // 2 x 16 KiB, layout [c][key][32] (swizzled slots)
  __shared__ __bf16 Vs[2][2 * 128 * 32];  // 2 x 16 KiB, layout [cc][d][32] (swizzled slots)
  __shared__ __bf16 Ps[8 * 16 * 64];      // 16 KiB, stride 64 + XOR swizzle (0 conflicts)
  const int t = threadIdx.x, lane = t & 63, w = t >> 6;
  const int h = blockIdx.y, qt = blockIdx.x;
  const float beta = sigmoidf_(ogate[0]) * 0.05f / 2048.0f;

  // per-lane swizzled 8-elem slot offset for K/V reads:
  // slot' = (lane>>4) ^ (row bits 1..2), row = *16 + (lane&15)
  const int rs8 = (((lane >> 4) ^ ((lane >> 1) & 3)) & 3) * 8;

  const int qrow = qt * 128 + w * 16 + (lane & 15);
  bf16x8 qf[4];
#pragma unroll
  for (int c = 0; c < 4; ++c)
    qf[c] = *(const bf16x8*)(Q + (size_t)qrow * DIM + h * 128 + c * 32 + (lane >> 4) * 8);

  f32x4 oacc[8] = {};
  float m_r[4], l_r[4];
#pragma unroll
  for (int r = 0; r < 4; ++r) { m_r[r] = -1e30f; l_r[r] = 0.f; }

  // stage tile kt into buffer buf (LDS dest linear, global source pre-swizzled)
  auto stage = [&](int buf, int kt) {
#pragma unroll
    for (int i = 0; i < 2; ++i) {
      const int o = i * 8192 + w * 1024 + lane * 16;   // linear LDS byte offset
      const int oz = o ^ (((o >> 7) & 3) << 4);        // swizzled logical address
      const int ke = (oz & 63) >> 1;                   // element offset in 32-wide row
      // K tile: [c][key][32]
      const int c = oz >> 12, key = (oz & 4095) >> 6;
      __builtin_amdgcn_global_load_lds(
          (gas_t)(Kg + (size_t)(kt + key) * DIM + h * 128 + c * 32 + ke),
          (las_t)(&Ks[buf][0] + (o >> 1)), 16, 0, 0);
      // V^T tile: [cc][d][32]
      const int d = (o & 8191) >> 6;
      __builtin_amdgcn_global_load_lds(
          (gas_t)(VT + (size_t)(h * 128 + d) * DIM + kt + i * 32 + ke),
          (las_t)(&Vs[buf][0] + (o >> 1)), 16, 0, 0);
    }
  };

  stage(0, 0);
  int p = 0;
  for (int kt = 0; kt < 2048; kt += 64) {
    __syncthreads();  // buf[p] staged (vmcnt drained here); buf[p^1] reads from t-1 done
    if (kt + 64 < 2048) stage(p ^ 1, kt + 64);  // prefetch next tile; drains at NEXT barrier

    // QK^T: sc[j] = 16q x 16key block j
    __builtin_amdgcn_s_setprio(1);
    f32x4 sc[4];
#pragma unroll
    for (int j = 0; j < 4; ++j) {
      f32x4 a = {};
#pragma unroll
      for (int c = 0; c < 4; ++c) {
        bf16x8 kf = *(const bf16x8*)(&Ks[p][0] + c * 2048 + (j * 16 + (lane & 15)) * 32 + rs8);
        a = __builtin_amdgcn_mfma_f32_16x16x32_bf16(qf[c], kf, a, 0, 0, 0);
      }
      sc[j] = a;
    }
    __builtin_amdgcn_s_setprio(0);
    // per-key position bias
#pragma unroll
    for (int j = 0; j < 4; ++j) {
      const float pb = beta * (float)(kt + j * 16 + (lane & 15));
#pragma unroll
      for (int r = 0; r < 4; ++r) sc[j][r] += pb;
    }
    // row max over 64 keys: regs then 16-lane butterfly
    float rmax[4];
#pragma unroll
    for (int r = 0; r < 4; ++r)
      rmax[r] = fmaxf(fmaxf(sc[0][r], sc[1][r]), fmaxf(sc[2][r], sc[3][r]));
#pragma unroll
    for (int msk = 1; msk < 16; msk <<= 1)
#pragma unroll
      for (int r = 0; r < 4; ++r) rmax[r] = fmaxf(rmax[r], __shfl_xor(rmax[r], msk, 64));

    // defer-max (exact): rescale only if some row's max grew; otherwise the
    // rescale factor is exp(0)=1 and skipping is bit-identical.
    bool need = (rmax[0] > m_r[0]) | (rmax[1] > m_r[1]) |
                (rmax[2] > m_r[2]) | (rmax[3] > m_r[3]);
    if (__any(need)) {
#pragma unroll
      for (int r = 0; r < 4; ++r) {
        const float mn = fmaxf(m_r[r], rmax[r]);
        const float al = __expf(m_r[r] - mn);
        m_r[r] = mn;
        l_r[r] *= al;
#pragma unroll
        for (int d = 0; d < 8; ++d) oacc[d][r] *= al;
      }
    }
#pragma unroll
    for (int j = 0; j < 4; ++j)
#pragma unroll
      for (int r = 0; r < 4; ++r) sc[j][r] = __expf(sc[j][r] - m_r[r]);

    float rs[4];
#pragma unroll
    for (int r = 0; r < 4; ++r) rs[r] = (sc[0][r] + sc[1][r]) + (sc[2][r] + sc[3][r]);
#pragma unroll
    for (int msk = 1; msk < 16; msk <<= 1)
#pragma unroll
      for (int r = 0; r < 4; ++r) rs[r] += __shfl_xor(rs[r], msk, 64);
#pragma unroll
    for (int r = 0; r < 4; ++r) l_r[r] += rs[r];

    // write P: logical [16 q][64 key] per wave, stride 64, elem ^= (q&7)<<3.
    // Wave-private region: same-wave LDS ordering via lgkmcnt, no barrier.
    {
      __bf16* pw = Ps + w * 1024;
#pragma unroll
      for (int j = 0; j < 4; ++j)
#pragma unroll
        for (int r = 0; r < 4; ++r) {
          const int q = (lane >> 4) * 4 + r;
          pw[(q * 64 + j * 16 + (lane & 15)) ^ ((q & 7) << 3)] = (__bf16)sc[j][r];
        }
    }

    // PV: oacc[d] += P(16x64) * V(64 x 16d-block)
    __builtin_amdgcn_s_setprio(1);
#pragma unroll
    for (int cc = 0; cc < 2; ++cc) {
      const int pe = (w * 1024 + (lane & 15) * 64 + cc * 32 + (lane >> 4) * 8) ^ ((lane & 7) << 3);
      bf16x8 pa = *(const bf16x8*)(Ps + pe);
#pragma unroll
      for (int d = 0; d < 8; ++d) {
        bf16x8 vf = *(const bf16x8*)(&Vs[p][0] + cc * 4096 + (d * 16 + (lane & 15)) * 32 + rs8);
        oacc[d] = __builtin_amdgcn_mfma_f32_16x16x32_bf16(pa, vf, oacc[d], 0, 0, 0);
      }
    }
    __builtin_amdgcn_s_setprio(0);
    p ^= 1;
  }

  // epilogue: normalize and store bf16 attention output [S][2048]
#pragma unroll
  for (int d = 0; d < 8; ++d)
#pragma unroll
    for (int r = 0; r < 4; ++r) {
      const int row = qt * 128 + w * 16 + (lane >> 4) * 4 + r;
      const int col = h * 128 + d * 16 + (lane & 15);
      O[(size_t)row * DIM + col] = (__bf16)(oacc[d][r] / l_r[r]);
    }
}

// ---------------------------------------------------------------------------
extern "C" void kernel_launch(void* const* d_in, const int* in_sizes, int n_in,
                              void* d_out, int out_size, void* d_ws, size_t ws_size,
                              hipStream_t stream) {
  const float* X  = (const float*)d_in[0];
  const float* Wq = (const float*)d_in[1];
  const float* bq = (const float*)d_in[2];
  const float* Wk = (const float*)d_in[3];
  const float* bk = (const float*)d_in[4];
  const float* Wv = (const float*)d_in[5];
  const float* bv = (const float*)d_in[6];
  const float* Wo = (const float*)d_in[7];
  const float* bo = (const float*)d_in[8];
  // gates: truth(9), balance(10), order(11), justice(12), harmony(13)
  const float* order_g   = (const float*)d_in[11];
  const float* justice_g = (const float*)d_in[12];

  __bf16* wsb = (__bf16*)d_ws;
  __bf16* Xb  = wsb + 0 * MAT;
  __bf16* Wqb = wsb + 1 * MAT;
  __bf16* Wkb = wsb + 2 * MAT;
  __bf16* Wvb = wsb + 3 * MAT;
  __bf16* Wob = wsb + 4 * MAT;
  __bf16* Qb  = wsb + 5 * MAT;
  __bf16* Kb  = wsb + 6 * MAT;
  __bf16* VTb = wsb + 7 * MAT;
  __bf16* Ab  = Xb;  // alias: X is dead after qkv_kernel (keeps ws use at 64 MB)

  cvt_kernel<<<dim3(4096, 5), 256, 0, stream>>>(X, Wq, Wk, Wv, Wo, wsb);
  qkv_kernel<<<dim3(48, 16), 256, 0, stream>>>(Xb, Wqb, Wkb, Wvb, bq, bk, bv, justice_g,
                                               Qb, Kb, VTb);
  attn_kernel<<<dim3(16, 16), 512, 0, stream>>>(Qb, Kb, VTb, order_g, Ab);
  outproj_kernel<<<dim3(32, 16), 256, 0, stream>>>(Ab, Wob, bo, (float*)d_out);
}

// Round 7
// 320.741 us; speedup vs baseline: 1.1252x; 1.0008x over previous
//
#include <hip/hip_runtime.h>

typedef __bf16 bf16x8 __attribute__((ext_vector_type(8)));
typedef __bf16 bf16x4 __attribute__((ext_vector_type(4)));
typedef float f32x4 __attribute__((ext_vector_type(4)));

typedef const __attribute__((address_space(1))) void* gas_t;
typedef __attribute__((address_space(3))) void* las_t;

static constexpr int DIM = 2048;
static constexpr size_t MAT = (size_t)DIM * DIM;  // 4194304 elements

__device__ __forceinline__ float sigmoidf_(float x) { return 1.f / (1.f + __expf(-x)); }

// ---------------------------------------------------------------------------
// fp32 -> bf16 conversion for X, Wq, Wk, Wv, Wo  (grid: (4096, 5), 256 thr)
// ---------------------------------------------------------------------------
__global__ void cvt_kernel(const float* __restrict__ x, const float* __restrict__ wq,
                           const float* __restrict__ wk, const float* __restrict__ wv,
                           const float* __restrict__ wo, __bf16* __restrict__ dst) {
  const float* s;
  switch (blockIdx.y) {
    case 0: s = x; break;
    case 1: s = wq; break;
    case 2: s = wk; break;
    case 3: s = wv; break;
    default: s = wo; break;
  }
  __bf16* d = dst + (size_t)blockIdx.y * MAT;
  size_t i = ((size_t)blockIdx.x * 256 + threadIdx.x) * 4;
  float4 v = *(const float4*)(s + i);
  bf16x4 ov;
  ov[0] = (__bf16)v.x; ov[1] = (__bf16)v.y; ov[2] = (__bf16)v.z; ov[3] = (__bf16)v.w;
  *(bf16x4*)(d + i) = ov;
}

// ---------------------------------------------------------------------------
// 128xBN GEMM body, BK=64 + row-XOR LDS swizzle: C = A * B^T (+bias, scale).
// Changes vs R1's BK=32 form (same 2-barriers-per-step skeleton, which
// measured best in R2/R5 A/Bs):
//  * BK=32 rows are 64 B = half the 128-B bank cycle; within a 16-lane read
//    phase lane>>4 is constant, so 16 rows hit 2 sixteen-byte quads -> 8-way
//    bank conflict on EVERY ds_read_b128 (R5 profile: qkv 6.3M conflict cy).
//    BK=64 makes rows 128 B and the both-sides involution byte^=(row&7)<<4
//    (pre-swizzled global source, XOR'd read slot) spreads each phase across
//    all 8 quads exactly twice -> 2-way = free (m136).
//  * BK=64 halves the barrier/vmcnt-drain count (64 -> 32 per output tile)
//    at identical staging bytes; drain stall amortizes over 2x MFMA.
//  * LDS <= 32 KiB so qkv keeps ~3 blocks/CU (the R5 64-KiB mistake avoided).
// ---------------------------------------------------------------------------
template <bool F32OUT, int BN>
__device__ __forceinline__ void gemm128(const __bf16* __restrict__ A, const __bf16* __restrict__ B,
                                        const float* __restrict__ bias, bool bias_row, float scale,
                                        void* __restrict__ Cout, int mtile, int ntile,
                                        __bf16* Asm, __bf16* Bsm) {
  constexpr int NJ = BN / 32;  // B-fragment blocks per wave
  const int t = threadIdx.x, lane = t & 63, w = t >> 6;
  const int wrow = (w >> 1) * 64, wcol = (w & 1) * (BN / 2);
  const int rbase = mtile * 128, cbase = ntile * BN;
  const int rx8 = (lane & 7) << 3;  // element-index XOR: row&7 into slot bits 3..5
  f32x4 acc[4][NJ] = {};

  for (int k0 = 0; k0 < DIM; k0 += 64) {
    __syncthreads();  // previous iteration's LDS reads complete
#pragma unroll
    for (int i = 0; i < 4; ++i) {  // A tile: 128 rows x 64 k x 2B = 16 KiB
      const int o = i * 4096 + t * 16;                   // linear LDS byte offset
      const int r = o >> 7;                              // row 0..127
      const int ke = ((o ^ ((r & 7) << 4)) & 127) >> 1;  // logical k elem (mult of 8)
      __builtin_amdgcn_global_load_lds((gas_t)(A + (size_t)(rbase + r) * DIM + k0 + ke),
                                       (las_t)(Asm + (o >> 1)), 16, 0, 0);
    }
#pragma unroll
    for (int i = 0; i < BN / 32; ++i) {  // B tile: BN rows x 64 k
      const int o = i * 4096 + t * 16;
      const int r = o >> 7;  // row 0..BN-1
      const int ke = ((o ^ ((r & 7) << 4)) & 127) >> 1;
      __builtin_amdgcn_global_load_lds((gas_t)(B + (size_t)(cbase + r) * DIM + k0 + ke),
                                       (las_t)(Bsm + (o >> 1)), 16, 0, 0);
    }
    __syncthreads();  // compiler drains vmcnt before barrier

#pragma unroll
    for (int hh = 0; hh < 2; ++hh) {  // two K=32 halves of the BK=64 tile
      const int kb = hh * 32 + (lane >> 4) * 8;  // logical elem offset in 64-wide row
      bf16x8 af[4], bf[NJ];
#pragma unroll
      for (int i = 0; i < 4; ++i)
        af[i] = *(const bf16x8*)(Asm + (wrow + i * 16 + (lane & 15)) * 64 + (kb ^ rx8));
#pragma unroll
      for (int j = 0; j < NJ; ++j)
        bf[j] = *(const bf16x8*)(Bsm + (wcol + j * 16 + (lane & 15)) * 64 + (kb ^ rx8));
#pragma unroll
      for (int i = 0; i < 4; ++i)
#pragma unroll
        for (int j = 0; j < NJ; ++j)
          acc[i][j] = __builtin_amdgcn_mfma_f32_16x16x32_bf16(af[i], bf[j], acc[i][j], 0, 0, 0);
    }
  }

  // epilogue: C/D layout col = lane&15, row = (lane>>4)*4 + r
#pragma unroll
  for (int i = 0; i < 4; ++i)
#pragma unroll
    for (int j = 0; j < NJ; ++j)
#pragma unroll
      for (int r = 0; r < 4; ++r) {
        const int row = rbase + wrow + i * 16 + (lane >> 4) * 4 + r;
        const int col = cbase + wcol + j * 16 + (lane & 15);
        float v = acc[i][j][r] + (bias_row ? bias[row] : bias[col]);
        v *= scale;
        if (F32OUT)
          ((float*)Cout)[(size_t)row * DIM + col] = v;
        else
          ((__bf16*)Cout)[(size_t)row * DIM + col] = (__bf16)v;
      }
}

// ---------------------------------------------------------------------------
// Fused QKV projections. grid (48,16): sel = x>>4 picks Q / K / V^T.
// ---------------------------------------------------------------------------
__global__ __launch_bounds__(256, 2) void qkv_kernel(
    const __bf16* __restrict__ Xb, const __bf16* __restrict__ Wqb, const __bf16* __restrict__ Wkb,
    const __bf16* __restrict__ Wvb, const float* __restrict__ bq, const float* __restrict__ bk,
    const float* __restrict__ bv, const float* __restrict__ jgate, __bf16* __restrict__ Qo,
    __bf16* __restrict__ Ko, __bf16* __restrict__ Vto) {
  __shared__ __bf16 Asm[128 * 64];
  __shared__ __bf16 Bsm[128 * 64];
  const int sel = blockIdx.x >> 4, nt = blockIdx.x & 15, mt = blockIdx.y;
  const __bf16 *A, *B;
  const float* bias;
  __bf16* C;
  bool brow = false;
  float sc = 1.f;
  if (sel == 0) {
    A = Xb; B = Wqb; bias = bq; C = Qo;
    sc = (1.f - 0.1f * sigmoidf_(jgate[0])) * 0.08838834764831843f;  // 1/sqrt(128)
  } else if (sel == 1) {
    A = Xb; B = Wkb; bias = bk; C = Ko;
  } else {
    A = Wvb; B = Xb; bias = bv; C = Vto; brow = true;
  }
  gemm128<false, 128>(A, B, bias, brow, sc, C, mt, nt, Asm, Bsm);
}

// ---------------------------------------------------------------------------
// Output projection: out = Ab Wo^T + bo  (fp32 out).  128x64 tiles ->
// grid (32,16) = 512 blocks = 2/CU.
// ---------------------------------------------------------------------------
__global__ __launch_bounds__(256, 2) void outproj_kernel(const __bf16* __restrict__ Ab,
                                                         const __bf16* __restrict__ Wob,
                                                         const float* __restrict__ bo,
                                                         float* __restrict__ Cout) {
  __shared__ __bf16 Asm[128 * 64];
  __shared__ __bf16 Bsm[64 * 64];
  gemm128<true, 64>(Ab, Wob, bo, false, 1.f, Cout, blockIdx.y, blockIdx.x, Asm, Bsm);
}

// ---------------------------------------------------------------------------
// Flash attention. grid (16 qtiles, 16 heads), 512 threads = 8 waves.
// R7: EXACT R1 body (its 88.3 us is the best measured single-pass attn).
// R6's setprio+defer-max bundle REVERTED (measured 97.6: setprio hurts in a
// barrier-locked 8-wave loop, m190; the defer branch de-pipelined oacc --
// VGPR 88->60).  Kept from R4/R6: bit-exact stride-64 XOR Ps (conflicts 0).
// ---------------------------------------------------------------------------
__global__ __launch_bounds__(512) void attn_kernel(const __bf16* __restrict__ Q,
                                                   const __bf16* __restrict__ Kg,
                                                   const __bf16* __restrict__ VT,
                                                   const float* __restrict__ ogate,
                                                   __bf16* __restrict__ O) {
  __shared__ __bf16 Ks[2][4 * 64 * 32];   // 2 x 16 KiB, layout [c][key][32] (swizzled slots)
  __shared__ __bf16 Vs[2][2 * 128 * 32];  // 2 x 16 KiB, layout [cc][d][32] (swizzled slots)
  __shared__ __bf16 Ps[8 * 16 * 64];      // 16 KiB, stride 64 + XOR swizzle (0 conflicts)
  const int t = threadIdx.x, lane = t & 63, w = t >> 6;
  const int h = blockIdx.y, qt = blockIdx.x;
  const float beta = sigmoidf_(ogate[0]) * 0.05f / 2048.0f;

  // per-lane swizzled 8-elem slot offset for K/V reads:
  // slot' = (lane>>4) ^ (row bits 1..2), row = *16 + (lane&15)
  const int rs8 = (((lane >> 4) ^ ((lane >> 1) & 3)) & 3) * 8;

  const int qrow = qt * 128 + w * 16 + (lane & 15);
  bf16x8 qf[4];
#pragma unroll
  for (int c = 0; c < 4; ++c)
    qf[c] = *(const bf16x8*)(Q + (size_t)qrow * DIM + h * 128 + c * 32 + (lane >> 4) * 8);

  f32x4 oacc[8] = {};
  float m_r[4], l_r[4];
#pragma unroll
  for (int r = 0; r < 4; ++r) { m_r[r] = -1e30f; l_r[r] = 0.f; }

  // stage tile kt into buffer buf (LDS dest linear, global source pre-swizzled)
  auto stage = [&](int buf, int kt) {
#pragma unroll
    for (int i = 0; i < 2; ++i) {
      const int o = i * 8192 + w * 1024 + lane * 16;   // linear LDS byte offset
      const int oz = o ^ (((o >> 7) & 3) << 4);        // swizzled logical address
      const int ke = (oz & 63) >> 1;                   // element offset in 32-wide row
      // K tile: [c][key][32]
      const int c = oz >> 12, key = (oz & 4095) >> 6;
      __builtin_amdgcn_global_load_lds(
          (gas_t)(Kg + (size_t)(kt + key) * DIM + h * 128 + c * 32 + ke),
          (las_t)(&Ks[buf][0] + (o >> 1)), 16, 0, 0);
      // V^T tile: [cc][d][32]
      const int d = (o & 8191) >> 6;
      __builtin_amdgcn_global_load_lds(
          (gas_t)(VT + (size_t)(h * 128 + d) * DIM + kt + i * 32 + ke),
          (las_t)(&Vs[buf][0] + (o >> 1)), 16, 0, 0);
    }
  };

  stage(0, 0);
  int p = 0;
  for (int kt = 0; kt < 2048; kt += 64) {
    __syncthreads();  // buf[p] staged (vmcnt drained here); buf[p^1] reads from t-1 done
    if (kt + 64 < 2048) stage(p ^ 1, kt + 64);  // prefetch next tile; drains at NEXT barrier

    // QK^T: sc[j] = 16q x 16key block j
    f32x4 sc[4];
#pragma unroll
    for (int j = 0; j < 4; ++j) {
      f32x4 a = {};
#pragma unroll
      for (int c = 0; c < 4; ++c) {
        bf16x8 kf = *(const bf16x8*)(&Ks[p][0] + c * 2048 + (j * 16 + (lane & 15)) * 32 + rs8);
        a = __builtin_amdgcn_mfma_f32_16x16x32_bf16(qf[c], kf, a, 0, 0, 0);
      }
      sc[j] = a;
    }
    // per-key position bias
#pragma unroll
    for (int j = 0; j < 4; ++j) {
      const float pb = beta * (float)(kt + j * 16 + (lane & 15));
#pragma unroll
      for (int r = 0; r < 4; ++r) sc[j][r] += pb;
    }
    // row max over 64 keys: regs then 16-lane butterfly
    float rmax[4];
#pragma unroll
    for (int r = 0; r < 4; ++r)
      rmax[r] = fmaxf(fmaxf(sc[0][r], sc[1][r]), fmaxf(sc[2][r], sc[3][r]));
#pragma unroll
    for (int msk = 1; msk < 16; msk <<= 1)
#pragma unroll
      for (int r = 0; r < 4; ++r) rmax[r] = fmaxf(rmax[r], __shfl_xor(rmax[r], msk, 64));

    float al[4];
#pragma unroll
    for (int r = 0; r < 4; ++r) {
      const float mn = fmaxf(m_r[r], rmax[r]);
      al[r] = __expf(m_r[r] - mn);
      m_r[r] = mn;
    }
#pragma unroll
    for (int j = 0; j < 4; ++j)
#pragma unroll
      for (int r = 0; r < 4; ++r) sc[j][r] = __expf(sc[j][r] - m_r[r]);

    float rs[4];
#pragma unroll
    for (int r = 0; r < 4; ++r) rs[r] = (sc[0][r] + sc[1][r]) + (sc[2][r] + sc[3][r]);
#pragma unroll
    for (int msk = 1; msk < 16; msk <<= 1)
#pragma unroll
      for (int r = 0; r < 4; ++r) rs[r] += __shfl_xor(rs[r], msk, 64);
#pragma unroll
    for (int r = 0; r < 4; ++r) l_r[r] = l_r[r] * al[r] + rs[r];
#pragma unroll
    for (int d = 0; d < 8; ++d)
#pragma unroll
      for (int r = 0; r < 4; ++r) oacc[d][r] *= al[r];

    // write P: logical [16 q][64 key] per wave, stride 64, elem ^= (q&7)<<3.
    // Wave-private region: same-wave LDS ordering via lgkmcnt, no barrier.
    {
      __bf16* pw = Ps + w * 1024;
#pragma unroll
      for (int j = 0; j < 4; ++j)
#pragma unroll
        for (int r = 0; r < 4; ++r) {
          const int q = (lane >> 4) * 4 + r;
          pw[(q * 64 + j * 16 + (lane & 15)) ^ ((q & 7) << 3)] = (__bf16)sc[j][r];
        }
    }

    // PV: oacc[d] += P(16x64) * V(64 x 16d-block)
#pragma unroll
    for (int cc = 0; cc < 2; ++cc) {
      const int pe = (w * 1024 + (lane & 15) * 64 + cc * 32 + (lane >> 4) * 8) ^ ((lane & 7) << 3);
      bf16x8 pa = *(const bf16x8*)(Ps + pe);
#pragma unroll
      for (int d = 0; d < 8; ++d) {
        bf16x8 vf = *(const bf16x8*)(&Vs[p][0] + cc * 4096 + (d * 16 + (lane & 15)) * 32 + rs8);
        oacc[d] = __builtin_amdgcn_mfma_f32_16x16x32_bf16(pa, vf, oacc[d], 0, 0, 0);
      }
    }
    p ^= 1;
  }

  // epilogue: normalize and store bf16 attention output [S][2048]
#pragma unroll
  for (int d = 0; d < 8; ++d)
#pragma unroll
    for (int r = 0; r < 4; ++r) {
      const int row = qt * 128 + w * 16 + (lane >> 4) * 4 + r;
      const int col = h * 128 + d * 16 + (lane & 15);
      O[(size_t)row * DIM + col] = (__bf16)(oacc[d][r] / l_r[r]);
    }
}

// ---------------------------------------------------------------------------
extern "C" void kernel_launch(void* const* d_in, const int* in_sizes, int n_in,
                              void* d_out, int out_size, void* d_ws, size_t ws_size,
                              hipStream_t stream) {
  const float* X  = (const float*)d_in[0];
  const float* Wq = (const float*)d_in[1];
  const float* bq = (const float*)d_in[2];
  const float* Wk = (const float*)d_in[3];
  const float* bk = (const float*)d_in[4];
  const float* Wv = (const float*)d_in[5];
  const float* bv = (const float*)d_in[6];
  const float* Wo = (const float*)d_in[7];
  const float* bo = (const float*)d_in[8];
  // gates: truth(9), balance(10), order(11), justice(12), harmony(13)
  const float* order_g   = (const float*)d_in[11];
  const float* justice_g = (const float*)d_in[12];

  __bf16* wsb = (__bf16*)d_ws;
  __bf16* Xb  = wsb + 0 * MAT;
  __bf16* Wqb = wsb + 1 * MAT;
  __bf16* Wkb = wsb + 2 * MAT;
  __bf16* Wvb = wsb + 3 * MAT;
  __bf16* Wob = wsb + 4 * MAT;
  __bf16* Qb  = wsb + 5 * MAT;
  __bf16* Kb  = wsb + 6 * MAT;
  __bf16* VTb = wsb + 7 * MAT;
  __bf16* Ab  = Xb;  // alias: X is dead after qkv_kernel (keeps ws use at 64 MB)

  cvt_kernel<<<dim3(4096, 5), 256, 0, stream>>>(X, Wq, Wk, Wv, Wo, wsb);
  qkv_kernel<<<dim3(48, 16), 256, 0, stream>>>(Xb, Wqb, Wkb, Wvb, bq, bk, bv, justice_g,
                                               Qb, Kb, VTb);
  attn_kernel<<<dim3(16, 16), 512, 0, stream>>>(Qb, Kb, VTb, order_g, Ab);
  outproj_kernel<<<dim3(32, 16), 256, 0, stream>>>(Ab, Wob, bo, (float*)d_out);
}

// Round 8
// 309.755 us; speedup vs baseline: 1.1651x; 1.0355x over previous
//
#include <hip/hip_runtime.h>

typedef __bf16 bf16x8 __attribute__((ext_vector_type(8)));
typedef __bf16 bf16x4 __attribute__((ext_vector_type(4)));
typedef float f32x4 __attribute__((ext_vector_type(4)));

typedef const __attribute__((address_space(1))) void* gas_t;
typedef __attribute__((address_space(3))) void* las_t;

static constexpr int DIM = 2048;
static constexpr size_t MAT = (size_t)DIM * DIM;  // 4194304 elements

__device__ __forceinline__ float sigmoidf_(float x) { return 1.f / (1.f + __expf(-x)); }

// ---------------------------------------------------------------------------
// fp32 -> bf16 conversion for X, Wq, Wk, Wv, Wo  (grid: (4096, 5), 256 thr)
// ---------------------------------------------------------------------------
__global__ void cvt_kernel(const float* __restrict__ x, const float* __restrict__ wq,
                           const float* __restrict__ wk, const float* __restrict__ wv,
                           const float* __restrict__ wo, __bf16* __restrict__ dst) {
  const float* s;
  switch (blockIdx.y) {
    case 0: s = x; break;
    case 1: s = wq; break;
    case 2: s = wk; break;
    case 3: s = wv; break;
    default: s = wo; break;
  }
  __bf16* d = dst + (size_t)blockIdx.y * MAT;
  size_t i = ((size_t)blockIdx.x * 256 + threadIdx.x) * 4;
  float4 v = *(const float4*)(s + i);
  bf16x4 ov;
  ov[0] = (__bf16)v.x; ov[1] = (__bf16)v.y; ov[2] = (__bf16)v.z; ov[3] = (__bf16)v.w;
  *(bf16x4*)(d + i) = ov;
}

// ---------------------------------------------------------------------------
// 128xBN GEMM body, BK=64 + row-XOR LDS swizzle: C = A * B^T (+bias, scale).
// KEPT from R7 (measured: non-attn 223.4 -> 211.7 us vs the BK=32 form).
//  * BK=64 rows are 128 B; both-sides involution byte^=(row&7)<<4 spreads
//    each 16-lane read phase across all 8 sixteen-byte quads -> 2-way = free
//    (was 8-way at BK=32: R5 profile showed qkv 6.3M conflict cycles).
//  * BK=64 halves the barrier/vmcnt-drain count at identical staging bytes.
//  * LDS <= 32 KiB so qkv keeps ~3 blocks/CU.
// ---------------------------------------------------------------------------
template <bool F32OUT, int BN>
__device__ __forceinline__ void gemm128(const __bf16* __restrict__ A, const __bf16* __restrict__ B,
                                        const float* __restrict__ bias, bool bias_row, float scale,
                                        void* __restrict__ Cout, int mtile, int ntile,
                                        __bf16* Asm, __bf16* Bsm) {
  constexpr int NJ = BN / 32;  // B-fragment blocks per wave
  const int t = threadIdx.x, lane = t & 63, w = t >> 6;
  const int wrow = (w >> 1) * 64, wcol = (w & 1) * (BN / 2);
  const int rbase = mtile * 128, cbase = ntile * BN;
  const int rx8 = (lane & 7) << 3;  // element-index XOR: row&7 into slot bits 3..5
  f32x4 acc[4][NJ] = {};

  for (int k0 = 0; k0 < DIM; k0 += 64) {
    __syncthreads();  // previous iteration's LDS reads complete
#pragma unroll
    for (int i = 0; i < 4; ++i) {  // A tile: 128 rows x 64 k x 2B = 16 KiB
      const int o = i * 4096 + t * 16;                   // linear LDS byte offset
      const int r = o >> 7;                              // row 0..127
      const int ke = ((o ^ ((r & 7) << 4)) & 127) >> 1;  // logical k elem (mult of 8)
      __builtin_amdgcn_global_load_lds((gas_t)(A + (size_t)(rbase + r) * DIM + k0 + ke),
                                       (las_t)(Asm + (o >> 1)), 16, 0, 0);
    }
#pragma unroll
    for (int i = 0; i < BN / 32; ++i) {  // B tile: BN rows x 64 k
      const int o = i * 4096 + t * 16;
      const int r = o >> 7;  // row 0..BN-1
      const int ke = ((o ^ ((r & 7) << 4)) & 127) >> 1;
      __builtin_amdgcn_global_load_lds((gas_t)(B + (size_t)(cbase + r) * DIM + k0 + ke),
                                       (las_t)(Bsm + (o >> 1)), 16, 0, 0);
    }
    __syncthreads();  // compiler drains vmcnt before barrier

#pragma unroll
    for (int hh = 0; hh < 2; ++hh) {  // two K=32 halves of the BK=64 tile
      const int kb = hh * 32 + (lane >> 4) * 8;  // logical elem offset in 64-wide row
      bf16x8 af[4], bf[NJ];
#pragma unroll
      for (int i = 0; i < 4; ++i)
        af[i] = *(const bf16x8*)(Asm + (wrow + i * 16 + (lane & 15)) * 64 + (kb ^ rx8));
#pragma unroll
      for (int j = 0; j < NJ; ++j)
        bf[j] = *(const bf16x8*)(Bsm + (wcol + j * 16 + (lane & 15)) * 64 + (kb ^ rx8));
#pragma unroll
      for (int i = 0; i < 4; ++i)
#pragma unroll
        for (int j = 0; j < NJ; ++j)
          acc[i][j] = __builtin_amdgcn_mfma_f32_16x16x32_bf16(af[i], bf[j], acc[i][j], 0, 0, 0);
    }
  }

  // epilogue: C/D layout col = lane&15, row = (lane>>4)*4 + r
#pragma unroll
  for (int i = 0; i < 4; ++i)
#pragma unroll
    for (int j = 0; j < NJ; ++j)
#pragma unroll
      for (int r = 0; r < 4; ++r) {
        const int row = rbase + wrow + i * 16 + (lane >> 4) * 4 + r;
        const int col = cbase + wcol + j * 16 + (lane & 15);
        float v = acc[i][j][r] + (bias_row ? bias[row] : bias[col]);
        v *= scale;
        if (F32OUT)
          ((float*)Cout)[(size_t)row * DIM + col] = v;
        else
          ((__bf16*)Cout)[(size_t)row * DIM + col] = (__bf16)v;
      }
}

// ---------------------------------------------------------------------------
// Fused QKV projections. grid (48,16): sel = x>>4 picks Q / K / V^T.
// ---------------------------------------------------------------------------
__global__ __launch_bounds__(256, 2) void qkv_kernel(
    const __bf16* __restrict__ Xb, const __bf16* __restrict__ Wqb, const __bf16* __restrict__ Wkb,
    const __bf16* __restrict__ Wvb, const float* __restrict__ bq, const float* __restrict__ bk,
    const float* __restrict__ bv, const float* __restrict__ jgate, __bf16* __restrict__ Qo,
    __bf16* __restrict__ Ko, __bf16* __restrict__ Vto) {
  __shared__ __bf16 Asm[128 * 64];
  __shared__ __bf16 Bsm[128 * 64];
  const int sel = blockIdx.x >> 4, nt = blockIdx.x & 15, mt = blockIdx.y;
  const __bf16 *A, *B;
  const float* bias;
  __bf16* C;
  bool brow = false;
  float sc = 1.f;
  if (sel == 0) {
    A = Xb; B = Wqb; bias = bq; C = Qo;
    sc = (1.f - 0.1f * sigmoidf_(jgate[0])) * 0.08838834764831843f;  // 1/sqrt(128)
  } else if (sel == 1) {
    A = Xb; B = Wkb; bias = bk; C = Ko;
  } else {
    A = Wvb; B = Xb; bias = bv; C = Vto; brow = true;
  }
  gemm128<false, 128>(A, B, bias, brow, sc, C, mt, nt, Asm, Bsm);
}

// ---------------------------------------------------------------------------
// Output projection: out = Ab Wo^T + bo  (fp32 out).  128x64 tiles ->
// grid (32,16) = 512 blocks = 2/CU.
// ---------------------------------------------------------------------------
__global__ __launch_bounds__(256, 2) void outproj_kernel(const __bf16* __restrict__ Ab,
                                                         const __bf16* __restrict__ Wob,
                                                         const float* __restrict__ bo,
                                                         float* __restrict__ Cout) {
  __shared__ __bf16 Asm[128 * 64];
  __shared__ __bf16 Bsm[64 * 64];
  gemm128<true, 64>(Ab, Wob, bo, false, 1.f, Cout, blockIdx.y, blockIdx.x, Asm, Bsm);
}

// ---------------------------------------------------------------------------
// Flash attention. grid (16 qtiles, 16 heads), 512 threads = 8 waves.
// EXACT R1 body (measured 88.3 us, VGPR 88).  R6/R7 isolated the Ps
// stride-64 XOR re-addressing as a -20% regressor: it dropped VGPR 88->60
// (compiler de-pipelined the K-loop) for zero occupancy gain at 1 block/CU.
// The stride-72 pad's ~0.5M residual 2-way conflicts are free (m136).
// Do NOT re-"fix" the Ps layout.
// ---------------------------------------------------------------------------
__global__ __launch_bounds__(512) void attn_kernel(const __bf16* __restrict__ Q,
                                                   const __bf16* __restrict__ Kg,
                                                   const __bf16* __restrict__ VT,
                                                   const float* __restrict__ ogate,
                                                   __bf16* __restrict__ O) {
  __shared__ __bf16 Ks[2][4 * 64 * 32];   // 2 x 16 KiB, layout [c][key][32] (swizzled slots)
  __shared__ __bf16 Vs[2][2 * 128 * 32];  // 2 x 16 KiB, layout [cc][d][32] (swizzled slots)
  __shared__ __bf16 Ps[8 * 16 * 72];      // 18 KiB, padded stride 72
  const int t = threadIdx.x, lane = t & 63, w = t >> 6;
  const int h = blockIdx.y, qt = blockIdx.x;
  const float beta = sigmoidf_(ogate[0]) * 0.05f / 2048.0f;

  // per-lane swizzled 8-elem slot offset for K/V reads:
  // slot' = (lane>>4) ^ (row bits 1..2), row = *16 + (lane&15)
  const int rs8 = (((lane >> 4) ^ ((lane >> 1) & 3)) & 3) * 8;

  const int qrow = qt * 128 + w * 16 + (lane & 15);
  bf16x8 qf[4];
#pragma unroll
  for (int c = 0; c < 4; ++c)
    qf[c] = *(const bf16x8*)(Q + (size_t)qrow * DIM + h * 128 + c * 32 + (lane >> 4) * 8);

  f32x4 oacc[8] = {};
  float m_r[4], l_r[4];
#pragma unroll
  for (int r = 0; r < 4; ++r) { m_r[r] = -1e30f; l_r[r] = 0.f; }

  // stage tile kt into buffer buf (LDS dest linear, global source pre-swizzled)
  auto stage = [&](int buf, int kt) {
#pragma unroll
    for (int i = 0; i < 2; ++i) {
      const int o = i * 8192 + w * 1024 + lane * 16;   // linear LDS byte offset
      const int oz = o ^ (((o >> 7) & 3) << 4);        // swizzled logical address
      const int ke = (oz & 63) >> 1;                   // element offset in 32-wide row
      // K tile: [c][key][32]
      const int c = oz >> 12, key = (oz & 4095) >> 6;
      __builtin_amdgcn_global_load_lds(
          (gas_t)(Kg + (size_t)(kt + key) * DIM + h * 128 + c * 32 + ke),
          (las_t)(&Ks[buf][0] + (o >> 1)), 16, 0, 0);
      // V^T tile: [cc][d][32]
      const int d = (o & 8191) >> 6;
      __builtin_amdgcn_global_load_lds(
          (gas_t)(VT + (size_t)(h * 128 + d) * DIM + kt + i * 32 + ke),
          (las_t)(&Vs[buf][0] + (o >> 1)), 16, 0, 0);
    }
  };

  stage(0, 0);
  int p = 0;
  for (int kt = 0; kt < 2048; kt += 64) {
    __syncthreads();  // buf[p] staged (vmcnt drained here); buf[p^1] reads from t-1 done
    if (kt + 64 < 2048) stage(p ^ 1, kt + 64);  // prefetch next tile; drains at NEXT barrier

    // QK^T: sc[j] = 16q x 16key block j
    f32x4 sc[4];
#pragma unroll
    for (int j = 0; j < 4; ++j) {
      f32x4 a = {};
#pragma unroll
      for (int c = 0; c < 4; ++c) {
        bf16x8 kf = *(const bf16x8*)(&Ks[p][0] + c * 2048 + (j * 16 + (lane & 15)) * 32 + rs8);
        a = __builtin_amdgcn_mfma_f32_16x16x32_bf16(qf[c], kf, a, 0, 0, 0);
      }
      sc[j] = a;
    }
    // per-key position bias
#pragma unroll
    for (int j = 0; j < 4; ++j) {
      const float pb = beta * (float)(kt + j * 16 + (lane & 15));
#pragma unroll
      for (int r = 0; r < 4; ++r) sc[j][r] += pb;
    }
    // row max over 64 keys: regs then 16-lane butterfly
    float rmax[4];
#pragma unroll
    for (int r = 0; r < 4; ++r)
      rmax[r] = fmaxf(fmaxf(sc[0][r], sc[1][r]), fmaxf(sc[2][r], sc[3][r]));
#pragma unroll
    for (int msk = 1; msk < 16; msk <<= 1)
#pragma unroll
      for (int r = 0; r < 4; ++r) rmax[r] = fmaxf(rmax[r], __shfl_xor(rmax[r], msk, 64));

    float al[4];
#pragma unroll
    for (int r = 0; r < 4; ++r) {
      const float mn = fmaxf(m_r[r], rmax[r]);
      al[r] = __expf(m_r[r] - mn);
      m_r[r] = mn;
    }
#pragma unroll
    for (int j = 0; j < 4; ++j)
#pragma unroll
      for (int r = 0; r < 4; ++r) sc[j][r] = __expf(sc[j][r] - m_r[r]);

    float rs[4];
#pragma unroll
    for (int r = 0; r < 4; ++r) rs[r] = (sc[0][r] + sc[1][r]) + (sc[2][r] + sc[3][r]);
#pragma unroll
    for (int msk = 1; msk < 16; msk <<= 1)
#pragma unroll
      for (int r = 0; r < 4; ++r) rs[r] += __shfl_xor(rs[r], msk, 64);
#pragma unroll
    for (int r = 0; r < 4; ++r) l_r[r] = l_r[r] * al[r] + rs[r];
#pragma unroll
    for (int d = 0; d < 8; ++d)
#pragma unroll
      for (int r = 0; r < 4; ++r) oacc[d][r] *= al[r];

    // write P (C-layout -> row-major [16 q][64 key], stride 72).
    // Wave-private region: same-wave LDS ordering via lgkmcnt, no barrier.
    {
      __bf16* pw = Ps + w * 1152;
#pragma unroll
      for (int j = 0; j < 4; ++j)
#pragma unroll
        for (int r = 0; r < 4; ++r)
          pw[((lane >> 4) * 4 + r) * 72 + j * 16 + (lane & 15)] = (__bf16)sc[j][r];
    }

    // PV: oacc[d] += P(16x64) * V(64 x 16d-block)
#pragma unroll
    for (int cc = 0; cc < 2; ++cc) {
      bf16x8 pa = *(const bf16x8*)(Ps + w * 1152 + (lane & 15) * 72 + cc * 32 + (lane >> 4) * 8);
#pragma unroll
      for (int d = 0; d < 8; ++d) {
        bf16x8 vf = *(const bf16x8*)(&Vs[p][0] + cc * 4096 + (d * 16 + (lane & 15)) * 32 + rs8);
        oacc[d] = __builtin_amdgcn_mfma_f32_16x16x32_bf16(pa, vf, oacc[d], 0, 0, 0);
      }
    }
    p ^= 1;
  }

  // epilogue: normalize and store bf16 attention output [S][2048]
#pragma unroll
  for (int d = 0; d < 8; ++d)
#pragma unroll
    for (int r = 0; r < 4; ++r) {
      const int row = qt * 128 + w * 16 + (lane >> 4) * 4 + r;
      const int col = h * 128 + d * 16 + (lane & 15);
      O[(size_t)row * DIM + col] = (__bf16)(oacc[d][r] / l_r[r]);
    }
}

// ---------------------------------------------------------------------------
extern "C" void kernel_launch(void* const* d_in, const int* in_sizes, int n_in,
                              void* d_out, int out_size, void* d_ws, size_t ws_size,
                              hipStream_t stream) {
  const float* X  = (const float*)d_in[0];
  const float* Wq = (const float*)d_in[1];
  const float* bq = (const float*)d_in[2];
  const float* Wk = (const float*)d_in[3];
  const float* bk = (const float*)d_in[4];
  const float* Wv = (const float*)d_in[5];
  const float* bv = (const float*)d_in[6];
  const float* Wo = (const float*)d_in[7];
  const float* bo = (const float*)d_in[8];
  // gates: truth(9), balance(10), order(11), justice(12), harmony(13)
  const float* order_g   = (const float*)d_in[11];
  const float* justice_g = (const float*)d_in[12];

  __bf16* wsb = (__bf16*)d_ws;
  __bf16* Xb  = wsb + 0 * MAT;
  __bf16* Wqb = wsb + 1 * MAT;
  __bf16* Wkb = wsb + 2 * MAT;
  __bf16* Wvb = wsb + 3 * MAT;
  __bf16* Wob = wsb + 4 * MAT;
  __bf16* Qb  = wsb + 5 * MAT;
  __bf16* Kb  = wsb + 6 * MAT;
  __bf16* VTb = wsb + 7 * MAT;
  __bf16* Ab  = Xb;  // alias: X is dead after qkv_kernel (keeps ws use at 64 MB)

  cvt_kernel<<<dim3(4096, 5), 256, 0, stream>>>(X, Wq, Wk, Wv, Wo, wsb);
  qkv_kernel<<<dim3(48, 16), 256, 0, stream>>>(Xb, Wqb, Wkb, Wvb, bq, bk, bv, justice_g,
                                               Qb, Kb, VTb);
  attn_kernel<<<dim3(16, 16), 512, 0, stream>>>(Qb, Kb, VTb, order_g, Ab);
  outproj_kernel<<<dim3(32, 16), 256, 0, stream>>>(Ab, Wob, bo, (float*)d_out);
}

// Round 9
// 308.019 us; speedup vs baseline: 1.1717x; 1.0056x over previous
//
#include <hip/hip_runtime.h>

typedef __bf16 bf16x8 __attribute__((ext_vector_type(8)));
typedef __bf16 bf16x4 __attribute__((ext_vector_type(4)));
typedef float f32x4 __attribute__((ext_vector_type(4)));

typedef const __attribute__((address_space(1))) void* gas_t;
typedef __attribute__((address_space(3))) void* las_t;

static constexpr int DIM = 2048;
static constexpr size_t MAT = (size_t)DIM * DIM;  // 4194304 elements

__device__ __forceinline__ float sigmoidf_(float x) { return 1.f / (1.f + __expf(-x)); }

// ---------------------------------------------------------------------------
// fp32 -> bf16 conversion for X, Wq, Wk, Wv, Wo  (grid: (4096, 5), 256 thr)
// ---------------------------------------------------------------------------
__global__ void cvt_kernel(const float* __restrict__ x, const float* __restrict__ wq,
                           const float* __restrict__ wk, const float* __restrict__ wv,
                           const float* __restrict__ wo, __bf16* __restrict__ dst) {
  const float* s;
  switch (blockIdx.y) {
    case 0: s = x; break;
    case 1: s = wq; break;
    case 2: s = wk; break;
    case 3: s = wv; break;
    default: s = wo; break;
  }
  __bf16* d = dst + (size_t)blockIdx.y * MAT;
  size_t i = ((size_t)blockIdx.x * 256 + threadIdx.x) * 4;
  float4 v = *(const float4*)(s + i);
  bf16x4 ov;
  ov[0] = (__bf16)v.x; ov[1] = (__bf16)v.y; ov[2] = (__bf16)v.z; ov[3] = (__bf16)v.w;
  *(bf16x4*)(d + i) = ov;
}

// ---------------------------------------------------------------------------
// 128xBN GEMM body, BK=64 + row-XOR LDS swizzle: C = A * B^T (+bias, scale).
// KEPT from R7 (measured: non-attn 223.4 -> 211.7 us vs the BK=32 form).
//  * BK=64 rows are 128 B; both-sides involution byte^=(row&7)<<4 spreads
//    each 16-lane read phase across all 8 sixteen-byte quads -> 2-way = free
//    (was 8-way at BK=32: R5 profile showed qkv 6.3M conflict cycles).
//  * BK=64 halves the barrier/vmcnt-drain count at identical staging bytes.
//  * LDS <= 32 KiB so qkv keeps ~3 blocks/CU.
// ---------------------------------------------------------------------------
template <bool F32OUT, int BN>
__device__ __forceinline__ void gemm128(const __bf16* __restrict__ A, const __bf16* __restrict__ B,
                                        const float* __restrict__ bias, bool bias_row, float scale,
                                        void* __restrict__ Cout, int mtile, int ntile,
                                        __bf16* Asm, __bf16* Bsm) {
  constexpr int NJ = BN / 32;  // B-fragment blocks per wave
  const int t = threadIdx.x, lane = t & 63, w = t >> 6;
  const int wrow = (w >> 1) * 64, wcol = (w & 1) * (BN / 2);
  const int rbase = mtile * 128, cbase = ntile * BN;
  const int rx8 = (lane & 7) << 3;  // element-index XOR: row&7 into slot bits 3..5
  f32x4 acc[4][NJ] = {};

  for (int k0 = 0; k0 < DIM; k0 += 64) {
    __syncthreads();  // previous iteration's LDS reads complete
#pragma unroll
    for (int i = 0; i < 4; ++i) {  // A tile: 128 rows x 64 k x 2B = 16 KiB
      const int o = i * 4096 + t * 16;                   // linear LDS byte offset
      const int r = o >> 7;                              // row 0..127
      const int ke = ((o ^ ((r & 7) << 4)) & 127) >> 1;  // logical k elem (mult of 8)
      __builtin_amdgcn_global_load_lds((gas_t)(A + (size_t)(rbase + r) * DIM + k0 + ke),
                                       (las_t)(Asm + (o >> 1)), 16, 0, 0);
    }
#pragma unroll
    for (int i = 0; i < BN / 32; ++i) {  // B tile: BN rows x 64 k
      const int o = i * 4096 + t * 16;
      const int r = o >> 7;  // row 0..BN-1
      const int ke = ((o ^ ((r & 7) << 4)) & 127) >> 1;
      __builtin_amdgcn_global_load_lds((gas_t)(B + (size_t)(cbase + r) * DIM + k0 + ke),
                                       (las_t)(Bsm + (o >> 1)), 16, 0, 0);
    }
    __syncthreads();  // compiler drains vmcnt before barrier

#pragma unroll
    for (int hh = 0; hh < 2; ++hh) {  // two K=32 halves of the BK=64 tile
      const int kb = hh * 32 + (lane >> 4) * 8;  // logical elem offset in 64-wide row
      bf16x8 af[4], bf[NJ];
#pragma unroll
      for (int i = 0; i < 4; ++i)
        af[i] = *(const bf16x8*)(Asm + (wrow + i * 16 + (lane & 15)) * 64 + (kb ^ rx8));
#pragma unroll
      for (int j = 0; j < NJ; ++j)
        bf[j] = *(const bf16x8*)(Bsm + (wcol + j * 16 + (lane & 15)) * 64 + (kb ^ rx8));
#pragma unroll
      for (int i = 0; i < 4; ++i)
#pragma unroll
        for (int j = 0; j < NJ; ++j)
          acc[i][j] = __builtin_amdgcn_mfma_f32_16x16x32_bf16(af[i], bf[j], acc[i][j], 0, 0, 0);
    }
  }

  // epilogue: C/D layout col = lane&15, row = (lane>>4)*4 + r
#pragma unroll
  for (int i = 0; i < 4; ++i)
#pragma unroll
    for (int j = 0; j < NJ; ++j)
#pragma unroll
      for (int r = 0; r < 4; ++r) {
        const int row = rbase + wrow + i * 16 + (lane >> 4) * 4 + r;
        const int col = cbase + wcol + j * 16 + (lane & 15);
        float v = acc[i][j][r] + (bias_row ? bias[row] : bias[col]);
        v *= scale;
        if (F32OUT)
          ((float*)Cout)[(size_t)row * DIM + col] = v;
        else
          ((__bf16*)Cout)[(size_t)row * DIM + col] = (__bf16)v;
      }
}

// ---------------------------------------------------------------------------
// Fused QKV projections. grid (48,16): sel = x>>4 picks Q / K / V^T.
// ---------------------------------------------------------------------------
__global__ __launch_bounds__(256, 2) void qkv_kernel(
    const __bf16* __restrict__ Xb, const __bf16* __restrict__ Wqb, const __bf16* __restrict__ Wkb,
    const __bf16* __restrict__ Wvb, const float* __restrict__ bq, const float* __restrict__ bk,
    const float* __restrict__ bv, const float* __restrict__ jgate, __bf16* __restrict__ Qo,
    __bf16* __restrict__ Ko, __bf16* __restrict__ Vto) {
  __shared__ __bf16 Asm[128 * 64];
  __shared__ __bf16 Bsm[128 * 64];
  const int sel = blockIdx.x >> 4, nt = blockIdx.x & 15, mt = blockIdx.y;
  const __bf16 *A, *B;
  const float* bias;
  __bf16* C;
  bool brow = false;
  float sc = 1.f;
  if (sel == 0) {
    A = Xb; B = Wqb; bias = bq; C = Qo;
    sc = (1.f - 0.1f * sigmoidf_(jgate[0])) * 0.08838834764831843f;  // 1/sqrt(128)
  } else if (sel == 1) {
    A = Xb; B = Wkb; bias = bk; C = Ko;
  } else {
    A = Wvb; B = Xb; bias = bv; C = Vto; brow = true;
  }
  gemm128<false, 128>(A, B, bias, brow, sc, C, mt, nt, Asm, Bsm);
}

// ---------------------------------------------------------------------------
// Output projection: out = Ab Wo^T + bo  (fp32 out).  128x64 tiles ->
// grid (32,16) = 512 blocks = 2/CU.
// ---------------------------------------------------------------------------
__global__ __launch_bounds__(256, 2) void outproj_kernel(const __bf16* __restrict__ Ab,
                                                         const __bf16* __restrict__ Wob,
                                                         const float* __restrict__ bo,
                                                         float* __restrict__ Cout) {
  __shared__ __bf16 Asm[128 * 64];
  __shared__ __bf16 Bsm[64 * 64];
  gemm128<true, 64>(Ab, Wob, bo, false, 1.f, Cout, blockIdx.y, blockIdx.x, Asm, Bsm);
}

// ---------------------------------------------------------------------------
// Flash attention. grid (16 qtiles, 16 heads), 512 threads = 8 waves.
// R9 = R8 body (Ps-72 pad, VGPR 88 -- do NOT re-"fix" the Ps layout, the
// stride-64 XOR de-pipelined the K-loop for -20%) + the R6-measured-positive
// bundle, now on the healthy base:
//  * T13 defer-max (bit-exact): skip the rescale pass (4 exp + 36 VALU) when
//    no row's tile-max exceeds the running max -- then every factor is
//    exp(0)=1.  __any keeps it wave-uniform.  VALUBusy(30%) = 2x MfmaUtil,
//    so deleting VALU from the critical chain is the right pipe.
//  * T5 setprio(1) around both MFMA clusters (attn-positive, m191; R6 bundle
//    measured +11.7us on the Ps-64 base).
// ---------------------------------------------------------------------------
__global__ __launch_bounds__(512) void attn_kernel(const __bf16* __restrict__ Q,
                                                   const __bf16* __restrict__ Kg,
                                                   const __bf16* __restrict__ VT,
                                                   const float* __restrict__ ogate,
                                                   __bf16* __restrict__ O) {
  __shared__ __bf16 Ks[2][4 * 64 * 32];   // 2 x 16 KiB, layout [c][key][32] (swizzled slots)
  __shared__ __bf16 Vs[2][2 * 128 * 32];  // 2 x 16 KiB, layout [cc][d][32] (swizzled slots)
  __shared__ __bf16 Ps[8 * 16 * 72];      // 18 KiB, padded stride 72
  const int t = threadIdx.x, lane = t & 63, w = t >> 6;
  const int h = blockIdx.y, qt = blockIdx.x;
  const float beta = sigmoidf_(ogate[0]) * 0.05f / 2048.0f;

  // per-lane swizzled 8-elem slot offset for K/V reads:
  // slot' = (lane>>4) ^ (row bits 1..2), row = *16 + (lane&15)
  const int rs8 = (((lane >> 4) ^ ((lane >> 1) & 3)) & 3) * 8;

  const int qrow = qt * 128 + w * 16 + (lane & 15);
  bf16x8 qf[4];
#pragma unroll
  for (int c = 0; c < 4; ++c)
    qf[c] = *(const bf16x8*)(Q + (size_t)qrow * DIM + h * 128 + c * 32 + (lane >> 4) * 8);

  f32x4 oacc[8] = {};
  float m_r[4], l_r[4];
#pragma unroll
  for (int r = 0; r < 4; ++r) { m_r[r] = -1e30f; l_r[r] = 0.f; }

  // stage tile kt into buffer buf (LDS dest linear, global source pre-swizzled)
  auto stage = [&](int buf, int kt) {
#pragma unroll
    for (int i = 0; i < 2; ++i) {
      const int o = i * 8192 + w * 1024 + lane * 16;   // linear LDS byte offset
      const int oz = o ^ (((o >> 7) & 3) << 4);        // swizzled logical address
      const int ke = (oz & 63) >> 1;                   // element offset in 32-wide row
      // K tile: [c][key][32]
      const int c = oz >> 12, key = (oz & 4095) >> 6;
      __builtin_amdgcn_global_load_lds(
          (gas_t)(Kg + (size_t)(kt + key) * DIM + h * 128 + c * 32 + ke),
          (las_t)(&Ks[buf][0] + (o >> 1)), 16, 0, 0);
      // V^T tile: [cc][d][32]
      const int d = (o & 8191) >> 6;
      __builtin_amdgcn_global_load_lds(
          (gas_t)(VT + (size_t)(h * 128 + d) * DIM + kt + i * 32 + ke),
          (las_t)(&Vs[buf][0] + (o >> 1)), 16, 0, 0);
    }
  };

  stage(0, 0);
  int p = 0;
  for (int kt = 0; kt < 2048; kt += 64) {
    __syncthreads();  // buf[p] staged (vmcnt drained here); buf[p^1] reads from t-1 done
    if (kt + 64 < 2048) stage(p ^ 1, kt + 64);  // prefetch next tile; drains at NEXT barrier

    // QK^T: sc[j] = 16q x 16key block j
    __builtin_amdgcn_s_setprio(1);
    f32x4 sc[4];
#pragma unroll
    for (int j = 0; j < 4; ++j) {
      f32x4 a = {};
#pragma unroll
      for (int c = 0; c < 4; ++c) {
        bf16x8 kf = *(const bf16x8*)(&Ks[p][0] + c * 2048 + (j * 16 + (lane & 15)) * 32 + rs8);
        a = __builtin_amdgcn_mfma_f32_16x16x32_bf16(qf[c], kf, a, 0, 0, 0);
      }
      sc[j] = a;
    }
    __builtin_amdgcn_s_setprio(0);
    // per-key position bias
#pragma unroll
    for (int j = 0; j < 4; ++j) {
      const float pb = beta * (float)(kt + j * 16 + (lane & 15));
#pragma unroll
      for (int r = 0; r < 4; ++r) sc[j][r] += pb;
    }
    // row max over 64 keys: regs then 16-lane butterfly
    float rmax[4];
#pragma unroll
    for (int r = 0; r < 4; ++r)
      rmax[r] = fmaxf(fmaxf(sc[0][r], sc[1][r]), fmaxf(sc[2][r], sc[3][r]));
#pragma unroll
    for (int msk = 1; msk < 16; msk <<= 1)
#pragma unroll
      for (int r = 0; r < 4; ++r) rmax[r] = fmaxf(rmax[r], __shfl_xor(rmax[r], msk, 64));

    // defer-max (bit-exact): if no row's max grew, every rescale factor is
    // exp(0)=1 -- skip the 4 exp + l/oacc multiplies entirely.
    bool need = (rmax[0] > m_r[0]) | (rmax[1] > m_r[1]) |
                (rmax[2] > m_r[2]) | (rmax[3] > m_r[3]);
    if (__any(need)) {
#pragma unroll
      for (int r = 0; r < 4; ++r) {
        const float mn = fmaxf(m_r[r], rmax[r]);
        const float al = __expf(m_r[r] - mn);
        m_r[r] = mn;
        l_r[r] *= al;
#pragma unroll
        for (int d = 0; d < 8; ++d) oacc[d][r] *= al;
      }
    }
#pragma unroll
    for (int j = 0; j < 4; ++j)
#pragma unroll
      for (int r = 0; r < 4; ++r) sc[j][r] = __expf(sc[j][r] - m_r[r]);

    float rs[4];
#pragma unroll
    for (int r = 0; r < 4; ++r) rs[r] = (sc[0][r] + sc[1][r]) + (sc[2][r] + sc[3][r]);
#pragma unroll
    for (int msk = 1; msk < 16; msk <<= 1)
#pragma unroll
      for (int r = 0; r < 4; ++r) rs[r] += __shfl_xor(rs[r], msk, 64);
#pragma unroll
    for (int r = 0; r < 4; ++r) l_r[r] += rs[r];

    // write P (C-layout -> row-major [16 q][64 key], stride 72).
    // Wave-private region: same-wave LDS ordering via lgkmcnt, no barrier.
    {
      __bf16* pw = Ps + w * 1152;
#pragma unroll
      for (int j = 0; j < 4; ++j)
#pragma unroll
        for (int r = 0; r < 4; ++r)
          pw[((lane >> 4) * 4 + r) * 72 + j * 16 + (lane & 15)] = (__bf16)sc[j][r];
    }

    // PV: oacc[d] += P(16x64) * V(64 x 16d-block)
    __builtin_amdgcn_s_setprio(1);
#pragma unroll
    for (int cc = 0; cc < 2; ++cc) {
      bf16x8 pa = *(const bf16x8*)(Ps + w * 1152 + (lane & 15) * 72 + cc * 32 + (lane >> 4) * 8);
#pragma unroll
      for (int d = 0; d < 8; ++d) {
        bf16x8 vf = *(const bf16x8*)(&Vs[p][0] + cc * 4096 + (d * 16 + (lane & 15)) * 32 + rs8);
        oacc[d] = __builtin_amdgcn_mfma_f32_16x16x32_bf16(pa, vf, oacc[d], 0, 0, 0);
      }
    }
    __builtin_amdgcn_s_setprio(0);
    p ^= 1;
  }

  // epilogue: normalize and store bf16 attention output [S][2048]
#pragma unroll
  for (int d = 0; d < 8; ++d)
#pragma unroll
    for (int r = 0; r < 4; ++r) {
      const int row = qt * 128 + w * 16 + (lane >> 4) * 4 + r;
      const int col = h * 128 + d * 16 + (lane & 15);
      O[(size_t)row * DIM + col] = (__bf16)(oacc[d][r] / l_r[r]);
    }
}

// ---------------------------------------------------------------------------
extern "C" void kernel_launch(void* const* d_in, const int* in_sizes, int n_in,
                              void* d_out, int out_size, void* d_ws, size_t ws_size,
                              hipStream_t stream) {
  const float* X  = (const float*)d_in[0];
  const float* Wq = (const float*)d_in[1];
  const float* bq = (const float*)d_in[2];
  const float* Wk = (const float*)d_in[3];
  const float* bk = (const float*)d_in[4];
  const float* Wv = (const float*)d_in[5];
  const float* bv = (const float*)d_in[6];
  const float* Wo = (const float*)d_in[7];
  const float* bo = (const float*)d_in[8];
  // gates: truth(9), balance(10), order(11), justice(12), harmony(13)
  const float* order_g   = (const float*)d_in[11];
  const float* justice_g = (const float*)d_in[12];

  __bf16* wsb = (__bf16*)d_ws;
  __bf16* Xb  = wsb + 0 * MAT;
  __bf16* Wqb = wsb + 1 * MAT;
  __bf16* Wkb = wsb + 2 * MAT;
  __bf16* Wvb = wsb + 3 * MAT;
  __bf16* Wob = wsb + 4 * MAT;
  __bf16* Qb  = wsb + 5 * MAT;
  __bf16* Kb  = wsb + 6 * MAT;
  __bf16* VTb = wsb + 7 * MAT;
  __bf16* Ab  = Xb;  // alias: X is dead after qkv_kernel (keeps ws use at 64 MB)

  cvt_kernel<<<dim3(4096, 5), 256, 0, stream>>>(X, Wq, Wk, Wv, Wo, wsb);
  qkv_kernel<<<dim3(48, 16), 256, 0, stream>>>(Xb, Wqb, Wkb, Wvb, bq, bk, bv, justice_g,
                                               Qb, Kb, VTb);
  attn_kernel<<<dim3(16, 16), 512, 0, stream>>>(Qb, Kb, VTb, order_g, Ab);
  outproj_kernel<<<dim3(32, 16), 256, 0, stream>>>(Ab, Wob, bo, (float*)d_out);
}

// Round 10
// 298.849 us; speedup vs baseline: 1.2076x; 1.0307x over previous
//
#include <hip/hip_runtime.h>

typedef __bf16 bf16x8 __attribute__((ext_vector_type(8)));
typedef __bf16 bf16x4 __attribute__((ext_vector_type(4)));
typedef float f32x4 __attribute__((ext_vector_type(4)));

typedef const __attribute__((address_space(1))) void* gas_t;
typedef __attribute__((address_space(3))) void* las_t;

static constexpr int DIM = 2048;
static constexpr size_t MAT = (size_t)DIM * DIM;  // 4194304 elements

__device__ __forceinline__ float sigmoidf_(float x) { return 1.f / (1.f + __expf(-x)); }

// ---------------------------------------------------------------------------
// fp32 -> bf16 conversion for X, Wq, Wk, Wv, Wo  (grid: (4096, 5), 256 thr)
// ---------------------------------------------------------------------------
__global__ void cvt_kernel(const float* __restrict__ x, const float* __restrict__ wq,
                           const float* __restrict__ wk, const float* __restrict__ wv,
                           const float* __restrict__ wo, __bf16* __restrict__ dst) {
  const float* s;
  switch (blockIdx.y) {
    case 0: s = x; break;
    case 1: s = wq; break;
    case 2: s = wk; break;
    case 3: s = wv; break;
    default: s = wo; break;
  }
  __bf16* d = dst + (size_t)blockIdx.y * MAT;
  size_t i = ((size_t)blockIdx.x * 256 + threadIdx.x) * 4;
  float4 v = *(const float4*)(s + i);
  bf16x4 ov;
  ov[0] = (__bf16)v.x; ov[1] = (__bf16)v.y; ov[2] = (__bf16)v.z; ov[3] = (__bf16)v.w;
  *(bf16x4*)(d + i) = ov;
}

// ---------------------------------------------------------------------------
// 128xBN GEMM body, BK=64 + row-XOR LDS swizzle: C = A * B^T (+bias, scale).
// Best-measured GEMM form (R7: non-attn 223.4 -> 211.7 us vs BK=32).
//  * BK=64 rows are 128 B; both-sides involution byte^=(row&7)<<4 spreads
//    each 16-lane read phase across all 8 sixteen-byte quads -> 2-way = free
//    (was 8-way at BK=32: R5 profile showed qkv 6.3M conflict cycles).
//  * BK=64 halves the barrier/vmcnt-drain count at identical staging bytes.
//  * LDS <= 32 KiB so qkv keeps 3 blocks/CU co-resident (m114 overlap).
// Rejected by measurement: dbuf+__syncthreads (R2 null), counted-vmcnt
// 4-deep pipeline (R5: -29 us, LDS occupancy + compiler defeats it).
// ---------------------------------------------------------------------------
template <bool F32OUT, int BN>
__device__ __forceinline__ void gemm128(const __bf16* __restrict__ A, const __bf16* __restrict__ B,
                                        const float* __restrict__ bias, bool bias_row, float scale,
                                        void* __restrict__ Cout, int mtile, int ntile,
                                        __bf16* Asm, __bf16* Bsm) {
  constexpr int NJ = BN / 32;  // B-fragment blocks per wave
  const int t = threadIdx.x, lane = t & 63, w = t >> 6;
  const int wrow = (w >> 1) * 64, wcol = (w & 1) * (BN / 2);
  const int rbase = mtile * 128, cbase = ntile * BN;
  const int rx8 = (lane & 7) << 3;  // element-index XOR: row&7 into slot bits 3..5
  f32x4 acc[4][NJ] = {};

  for (int k0 = 0; k0 < DIM; k0 += 64) {
    __syncthreads();  // previous iteration's LDS reads complete
#pragma unroll
    for (int i = 0; i < 4; ++i) {  // A tile: 128 rows x 64 k x 2B = 16 KiB
      const int o = i * 4096 + t * 16;                   // linear LDS byte offset
      const int r = o >> 7;                              // row 0..127
      const int ke = ((o ^ ((r & 7) << 4)) & 127) >> 1;  // logical k elem (mult of 8)
      __builtin_amdgcn_global_load_lds((gas_t)(A + (size_t)(rbase + r) * DIM + k0 + ke),
                                       (las_t)(Asm + (o >> 1)), 16, 0, 0);
    }
#pragma unroll
    for (int i = 0; i < BN / 32; ++i) {  // B tile: BN rows x 64 k
      const int o = i * 4096 + t * 16;
      const int r = o >> 7;  // row 0..BN-1
      const int ke = ((o ^ ((r & 7) << 4)) & 127) >> 1;
      __builtin_amdgcn_global_load_lds((gas_t)(B + (size_t)(cbase + r) * DIM + k0 + ke),
                                       (las_t)(Bsm + (o >> 1)), 16, 0, 0);
    }
    __syncthreads();  // compiler drains vmcnt before barrier

#pragma unroll
    for (int hh = 0; hh < 2; ++hh) {  // two K=32 halves of the BK=64 tile
      const int kb = hh * 32 + (lane >> 4) * 8;  // logical elem offset in 64-wide row
      bf16x8 af[4], bf[NJ];
#pragma unroll
      for (int i = 0; i < 4; ++i)
        af[i] = *(const bf16x8*)(Asm + (wrow + i * 16 + (lane & 15)) * 64 + (kb ^ rx8));
#pragma unroll
      for (int j = 0; j < NJ; ++j)
        bf[j] = *(const bf16x8*)(Bsm + (wcol + j * 16 + (lane & 15)) * 64 + (kb ^ rx8));
#pragma unroll
      for (int i = 0; i < 4; ++i)
#pragma unroll
        for (int j = 0; j < NJ; ++j)
          acc[i][j] = __builtin_amdgcn_mfma_f32_16x16x32_bf16(af[i], bf[j], acc[i][j], 0, 0, 0);
    }
  }

  // epilogue: C/D layout col = lane&15, row = (lane>>4)*4 + r
#pragma unroll
  for (int i = 0; i < 4; ++i)
#pragma unroll
    for (int j = 0; j < NJ; ++j)
#pragma unroll
      for (int r = 0; r < 4; ++r) {
        const int row = rbase + wrow + i * 16 + (lane >> 4) * 4 + r;
        const int col = cbase + wcol + j * 16 + (lane & 15);
        float v = acc[i][j][r] + (bias_row ? bias[row] : bias[col]);
        v *= scale;
        if (F32OUT)
          ((float*)Cout)[(size_t)row * DIM + col] = v;
        else
          ((__bf16*)Cout)[(size_t)row * DIM + col] = (__bf16)v;
      }
}

// ---------------------------------------------------------------------------
// Fused QKV projections. grid (48,16): sel = x>>4 picks Q / K / V^T.
// ---------------------------------------------------------------------------
__global__ __launch_bounds__(256, 2) void qkv_kernel(
    const __bf16* __restrict__ Xb, const __bf16* __restrict__ Wqb, const __bf16* __restrict__ Wkb,
    const __bf16* __restrict__ Wvb, const float* __restrict__ bq, const float* __restrict__ bk,
    const float* __restrict__ bv, const float* __restrict__ jgate, __bf16* __restrict__ Qo,
    __bf16* __restrict__ Ko, __bf16* __restrict__ Vto) {
  __shared__ __bf16 Asm[128 * 64];
  __shared__ __bf16 Bsm[128 * 64];
  const int sel = blockIdx.x >> 4, nt = blockIdx.x & 15, mt = blockIdx.y;
  const __bf16 *A, *B;
  const float* bias;
  __bf16* C;
  bool brow = false;
  float sc = 1.f;
  if (sel == 0) {
    A = Xb; B = Wqb; bias = bq; C = Qo;
    sc = (1.f - 0.1f * sigmoidf_(jgate[0])) * 0.08838834764831843f;  // 1/sqrt(128)
  } else if (sel == 1) {
    A = Xb; B = Wkb; bias = bk; C = Ko;
  } else {
    A = Wvb; B = Xb; bias = bv; C = Vto; brow = true;
  }
  gemm128<false, 128>(A, B, bias, brow, sc, C, mt, nt, Asm, Bsm);
}

// ---------------------------------------------------------------------------
// Output projection: out = Ab Wo^T + bo  (fp32 out).  128x64 tiles ->
// grid (32,16) = 512 blocks = 2/CU.
// ---------------------------------------------------------------------------
__global__ __launch_bounds__(256, 2) void outproj_kernel(const __bf16* __restrict__ Ab,
                                                         const __bf16* __restrict__ Wob,
                                                         const float* __restrict__ bo,
                                                         float* __restrict__ Cout) {
  __shared__ __bf16 Asm[128 * 64];
  __shared__ __bf16 Bsm[64 * 64];
  gemm128<true, 64>(Ab, Wob, bo, false, 1.f, Cout, blockIdx.y, blockIdx.x, Asm, Bsm);
}

// ---------------------------------------------------------------------------
// Flash attention. grid (16 qtiles, 16 heads), 512 threads = 8 waves.
// EXACT R8 body -- measured best twice (88.3 / 94.0 us).  Decisions locked
// by the R6-R9 measurement matrix:
//  * Ps stride-72 pad, NOT stride-64 XOR: the XOR re-addressing dropped
//    VGPR 88->60 (compiler de-pipelined the K-loop) for -20%; the pad's
//    ~524K residual 2-way conflicts are free (m136).
//  * NO setprio / defer-max: on this well-pipelined base the bundle is
//    -7.4 us (R9); it only helped the de-pipelined Ps-64 base (R6).
//    This is m190's lockstep-negative reproduced: 8 barrier-synced waves
//    behave like GEMM lockstep, not independent-wave attention.
//  * K/V source-swizzle + 2-phase prefetch (R0->R1, -15 us) is the one
//    attn optimization that survived measurement.
// ---------------------------------------------------------------------------
__global__ __launch_bounds__(512) void attn_kernel(const __bf16* __restrict__ Q,
                                                   const __bf16* __restrict__ Kg,
                                                   const __bf16* __restrict__ VT,
                                                   const float* __restrict__ ogate,
                                                   __bf16* __restrict__ O) {
  __shared__ __bf16 Ks[2][4 * 64 * 32];   // 2 x 16 KiB, layout [c][key][32] (swizzled slots)
  __shared__ __bf16 Vs[2][2 * 128 * 32];  // 2 x 16 KiB, layout [cc][d][32] (swizzled slots)
  __shared__ __bf16 Ps[8 * 16 * 72];      // 18 KiB, padded stride 72
  const int t = threadIdx.x, lane = t & 63, w = t >> 6;
  const int h = blockIdx.y, qt = blockIdx.x;
  const float beta = sigmoidf_(ogate[0]) * 0.05f / 2048.0f;

  // per-lane swizzled 8-elem slot offset for K/V reads:
  // slot' = (lane>>4) ^ (row bits 1..2), row = *16 + (lane&15)
  const int rs8 = (((lane >> 4) ^ ((lane >> 1) & 3)) & 3) * 8;

  const int qrow = qt * 128 + w * 16 + (lane & 15);
  bf16x8 qf[4];
#pragma unroll
  for (int c = 0; c < 4; ++c)
    qf[c] = *(const bf16x8*)(Q + (size_t)qrow * DIM + h * 128 + c * 32 + (lane >> 4) * 8);

  f32x4 oacc[8] = {};
  float m_r[4], l_r[4];
#pragma unroll
  for (int r = 0; r < 4; ++r) { m_r[r] = -1e30f; l_r[r] = 0.f; }

  // stage tile kt into buffer buf (LDS dest linear, global source pre-swizzled)
  auto stage = [&](int buf, int kt) {
#pragma unroll
    for (int i = 0; i < 2; ++i) {
      const int o = i * 8192 + w * 1024 + lane * 16;   // linear LDS byte offset
      const int oz = o ^ (((o >> 7) & 3) << 4);        // swizzled logical address
      const int ke = (oz & 63) >> 1;                   // element offset in 32-wide row
      // K tile: [c][key][32]
      const int c = oz >> 12, key = (oz & 4095) >> 6;
      __builtin_amdgcn_global_load_lds(
          (gas_t)(Kg + (size_t)(kt + key) * DIM + h * 128 + c * 32 + ke),
          (las_t)(&Ks[buf][0] + (o >> 1)), 16, 0, 0);
      // V^T tile: [cc][d][32]
      const int d = (o & 8191) >> 6;
      __builtin_amdgcn_global_load_lds(
          (gas_t)(VT + (size_t)(h * 128 + d) * DIM + kt + i * 32 + ke),
          (las_t)(&Vs[buf][0] + (o >> 1)), 16, 0, 0);
    }
  };

  stage(0, 0);
  int p = 0;
  for (int kt = 0; kt < 2048; kt += 64) {
    __syncthreads();  // buf[p] staged (vmcnt drained here); buf[p^1] reads from t-1 done
    if (kt + 64 < 2048) stage(p ^ 1, kt + 64);  // prefetch next tile; drains at NEXT barrier

    // QK^T: sc[j] = 16q x 16key block j
    f32x4 sc[4];
#pragma unroll
    for (int j = 0; j < 4; ++j) {
      f32x4 a = {};
#pragma unroll
      for (int c = 0; c < 4; ++c) {
        bf16x8 kf = *(const bf16x8*)(&Ks[p][0] + c * 2048 + (j * 16 + (lane & 15)) * 32 + rs8);
        a = __builtin_amdgcn_mfma_f32_16x16x32_bf16(qf[c], kf, a, 0, 0, 0);
      }
      sc[j] = a;
    }
    // per-key position bias
#pragma unroll
    for (int j = 0; j < 4; ++j) {
      const float pb = beta * (float)(kt + j * 16 + (lane & 15));
#pragma unroll
      for (int r = 0; r < 4; ++r) sc[j][r] += pb;
    }
    // row max over 64 keys: regs then 16-lane butterfly
    float rmax[4];
#pragma unroll
    for (int r = 0; r < 4; ++r)
      rmax[r] = fmaxf(fmaxf(sc[0][r], sc[1][r]), fmaxf(sc[2][r], sc[3][r]));
#pragma unroll
    for (int msk = 1; msk < 16; msk <<= 1)
#pragma unroll
      for (int r = 0; r < 4; ++r) rmax[r] = fmaxf(rmax[r], __shfl_xor(rmax[r], msk, 64));

    float al[4];
#pragma unroll
    for (int r = 0; r < 4; ++r) {
      const float mn = fmaxf(m_r[r], rmax[r]);
      al[r] = __expf(m_r[r] - mn);
      m_r[r] = mn;
    }
#pragma unroll
    for (int j = 0; j < 4; ++j)
#pragma unroll
      for (int r = 0; r < 4; ++r) sc[j][r] = __expf(sc[j][r] - m_r[r]);

    float rs[4];
#pragma unroll
    for (int r = 0; r < 4; ++r) rs[r] = (sc[0][r] + sc[1][r]) + (sc[2][r] + sc[3][r]);
#pragma unroll
    for (int msk = 1; msk < 16; msk <<= 1)
#pragma unroll
      for (int r = 0; r < 4; ++r) rs[r] += __shfl_xor(rs[r], msk, 64);
#pragma unroll
    for (int r = 0; r < 4; ++r) l_r[r] = l_r[r] * al[r] + rs[r];
#pragma unroll
    for (int d = 0; d < 8; ++d)
#pragma unroll
      for (int r = 0; r < 4; ++r) oacc[d][r] *= al[r];

    // write P (C-layout -> row-major [16 q][64 key], stride 72).
    // Wave-private region: same-wave LDS ordering via lgkmcnt, no barrier.
    {
      __bf16* pw = Ps + w * 1152;
#pragma unroll
      for (int j = 0; j < 4; ++j)
#pragma unroll
        for (int r = 0; r < 4; ++r)
          pw[((lane >> 4) * 4 + r) * 72 + j * 16 + (lane & 15)] = (__bf16)sc[j][r];
    }

    // PV: oacc[d] += P(16x64) * V(64 x 16d-block)
#pragma unroll
    for (int cc = 0; cc < 2; ++cc) {
      bf16x8 pa = *(const bf16x8*)(Ps + w * 1152 + (lane & 15) * 72 + cc * 32 + (lane >> 4) * 8);
#pragma unroll
      for (int d = 0; d < 8; ++d) {
        bf16x8 vf = *(const bf16x8*)(&Vs[p][0] + cc * 4096 + (d * 16 + (lane & 15)) * 32 + rs8);
        oacc[d] = __builtin_amdgcn_mfma_f32_16x16x32_bf16(pa, vf, oacc[d], 0, 0, 0);
      }
    }
    p ^= 1;
  }

  // epilogue: normalize and store bf16 attention output [S][2048]
#pragma unroll
  for (int d = 0; d < 8; ++d)
#pragma unroll
    for (int r = 0; r < 4; ++r) {
      const int row = qt * 128 + w * 16 + (lane >> 4) * 4 + r;
      const int col = h * 128 + d * 16 + (lane & 15);
      O[(size_t)row * DIM + col] = (__bf16)(oacc[d][r] / l_r[r]);
    }
}

// ---------------------------------------------------------------------------
extern "C" void kernel_launch(void* const* d_in, const int* in_sizes, int n_in,
                              void* d_out, int out_size, void* d_ws, size_t ws_size,
                              hipStream_t stream) {
  const float* X  = (const float*)d_in[0];
  const float* Wq = (const float*)d_in[1];
  const float* bq = (const float*)d_in[2];
  const float* Wk = (const float*)d_in[3];
  const float* bk = (const float*)d_in[4];
  const float* Wv = (const float*)d_in[5];
  const float* bv = (const float*)d_in[6];
  const float* Wo = (const float*)d_in[7];
  const float* bo = (const float*)d_in[8];
  // gates: truth(9), balance(10), order(11), justice(12), harmony(13)
  const float* order_g   = (const float*)d_in[11];
  const float* justice_g = (const float*)d_in[12];

  __bf16* wsb = (__bf16*)d_ws;
  __bf16* Xb  = wsb + 0 * MAT;
  __bf16* Wqb = wsb + 1 * MAT;
  __bf16* Wkb = wsb + 2 * MAT;
  __bf16* Wvb = wsb + 3 * MAT;
  __bf16* Wob = wsb + 4 * MAT;
  __bf16* Qb  = wsb + 5 * MAT;
  __bf16* Kb  = wsb + 6 * MAT;
  __bf16* VTb = wsb + 7 * MAT;
  __bf16* Ab  = Xb;  // alias: X is dead after qkv_kernel (keeps ws use at 64 MB)

  cvt_kernel<<<dim3(4096, 5), 256, 0, stream>>>(X, Wq, Wk, Wv, Wo, wsb);
  qkv_kernel<<<dim3(48, 16), 256, 0, stream>>>(Xb, Wqb, Wkb, Wvb, bq, bk, bv, justice_g,
                                               Qb, Kb, VTb);
  attn_kernel<<<dim3(16, 16), 512, 0, stream>>>(Qb, Kb, VTb, order_g, Ab);
  outproj_kernel<<<dim3(32, 16), 256, 0, stream>>>(Ab, Wob, bo, (float*)d_out);
}

// Round 12
// 290.888 us; speedup vs baseline: 1.2407x; 1.0274x over previous
//
#include <hip/hip_runtime.h>

typedef __bf16 bf16x8 __attribute__((ext_vector_type(8)));
typedef __bf16 bf16x4 __attribute__((ext_vector_type(4)));
typedef float f32x4 __attribute__((ext_vector_type(4)));

typedef const __attribute__((address_space(1))) void* gas_t;
typedef __attribute__((address_space(3))) void* las_t;

static constexpr int DIM = 2048;
static constexpr size_t MAT = (size_t)DIM * DIM;  // 4194304 elements

__device__ __forceinline__ float sigmoidf_(float x) { return 1.f / (1.f + __expf(-x)); }

// ---------------------------------------------------------------------------
// fp32 -> bf16 conversion for X, Wq, Wk, Wv, Wo  (grid: (4096, 5), 256 thr)
// ---------------------------------------------------------------------------
__global__ void cvt_kernel(const float* __restrict__ x, const float* __restrict__ wq,
                           const float* __restrict__ wk, const float* __restrict__ wv,
                           const float* __restrict__ wo, __bf16* __restrict__ dst) {
  const float* s;
  switch (blockIdx.y) {
    case 0: s = x; break;
    case 1: s = wq; break;
    case 2: s = wk; break;
    case 3: s = wv; break;
    default: s = wo; break;
  }
  __bf16* d = dst + (size_t)blockIdx.y * MAT;
  size_t i = ((size_t)blockIdx.x * 256 + threadIdx.x) * 4;
  float4 v = *(const float4*)(s + i);
  bf16x4 ov;
  ov[0] = (__bf16)v.x; ov[1] = (__bf16)v.y; ov[2] = (__bf16)v.z; ov[3] = (__bf16)v.w;
  *(bf16x4*)(d + i) = ov;
}

// ---------------------------------------------------------------------------
// 128xBN GEMM body, BK=64 + row-XOR LDS swizzle: C = A * B^T (+bias, scale).
// Best-measured GEMM form (R7: non-attn 223.4 -> 211.7 us vs BK=32).
// ---------------------------------------------------------------------------
template <bool F32OUT, int BN>
__device__ __forceinline__ void gemm128(const __bf16* __restrict__ A, const __bf16* __restrict__ B,
                                        const float* __restrict__ bias, bool bias_row, float scale,
                                        void* __restrict__ Cout, int mtile, int ntile,
                                        __bf16* Asm, __bf16* Bsm) {
  constexpr int NJ = BN / 32;  // B-fragment blocks per wave
  const int t = threadIdx.x, lane = t & 63, w = t >> 6;
  const int wrow = (w >> 1) * 64, wcol = (w & 1) * (BN / 2);
  const int rbase = mtile * 128, cbase = ntile * BN;
  const int rx8 = (lane & 7) << 3;  // element-index XOR: row&7 into slot bits 3..5
  f32x4 acc[4][NJ] = {};

  for (int k0 = 0; k0 < DIM; k0 += 64) {
    __syncthreads();  // previous iteration's LDS reads complete
#pragma unroll
    for (int i = 0; i < 4; ++i) {  // A tile: 128 rows x 64 k x 2B = 16 KiB
      const int o = i * 4096 + t * 16;                   // linear LDS byte offset
      const int r = o >> 7;                              // row 0..127
      const int ke = ((o ^ ((r & 7) << 4)) & 127) >> 1;  // logical k elem (mult of 8)
      __builtin_amdgcn_global_load_lds((gas_t)(A + (size_t)(rbase + r) * DIM + k0 + ke),
                                       (las_t)(Asm + (o >> 1)), 16, 0, 0);
    }
#pragma unroll
    for (int i = 0; i < BN / 32; ++i) {  // B tile: BN rows x 64 k
      const int o = i * 4096 + t * 16;
      const int r = o >> 7;  // row 0..BN-1
      const int ke = ((o ^ ((r & 7) << 4)) & 127) >> 1;
      __builtin_amdgcn_global_load_lds((gas_t)(B + (size_t)(cbase + r) * DIM + k0 + ke),
                                       (las_t)(Bsm + (o >> 1)), 16, 0, 0);
    }
    __syncthreads();  // compiler drains vmcnt before barrier

#pragma unroll
    for (int hh = 0; hh < 2; ++hh) {  // two K=32 halves of the BK=64 tile
      const int kb = hh * 32 + (lane >> 4) * 8;  // logical elem offset in 64-wide row
      bf16x8 af[4], bf[NJ];
#pragma unroll
      for (int i = 0; i < 4; ++i)
        af[i] = *(const bf16x8*)(Asm + (wrow + i * 16 + (lane & 15)) * 64 + (kb ^ rx8));
#pragma unroll
      for (int j = 0; j < NJ; ++j)
        bf[j] = *(const bf16x8*)(Bsm + (wcol + j * 16 + (lane & 15)) * 64 + (kb ^ rx8));
#pragma unroll
      for (int i = 0; i < 4; ++i)
#pragma unroll
        for (int j = 0; j < NJ; ++j)
          acc[i][j] = __builtin_amdgcn_mfma_f32_16x16x32_bf16(af[i], bf[j], acc[i][j], 0, 0, 0);
    }
  }

  // epilogue: C/D layout col = lane&15, row = (lane>>4)*4 + r
#pragma unroll
  for (int i = 0; i < 4; ++i)
#pragma unroll
    for (int j = 0; j < NJ; ++j)
#pragma unroll
      for (int r = 0; r < 4; ++r) {
        const int row = rbase + wrow + i * 16 + (lane >> 4) * 4 + r;
        const int col = cbase + wcol + j * 16 + (lane & 15);
        float v = acc[i][j][r] + (bias_row ? bias[row] : bias[col]);
        v *= scale;
        if (F32OUT)
          ((float*)Cout)[(size_t)row * DIM + col] = v;
        else
          ((__bf16*)Cout)[(size_t)row * DIM + col] = (__bf16)v;
      }
}

// ---------------------------------------------------------------------------
// Fused QKV projections. grid (48,16): sel = x>>4 picks Q / K / V^T.
// ---------------------------------------------------------------------------
__global__ __launch_bounds__(256, 2) void qkv_kernel(
    const __bf16* __restrict__ Xb, const __bf16* __restrict__ Wqb, const __bf16* __restrict__ Wkb,
    const __bf16* __restrict__ Wvb, const float* __restrict__ bq, const float* __restrict__ bk,
    const float* __restrict__ bv, const float* __restrict__ jgate, __bf16* __restrict__ Qo,
    __bf16* __restrict__ Ko, __bf16* __restrict__ Vto) {
  __shared__ __bf16 Asm[128 * 64];
  __shared__ __bf16 Bsm[128 * 64];
  const int sel = blockIdx.x >> 4, nt = blockIdx.x & 15, mt = blockIdx.y;
  const __bf16 *A, *B;
  const float* bias;
  __bf16* C;
  bool brow = false;
  float sc = 1.f;
  if (sel == 0) {
    A = Xb; B = Wqb; bias = bq; C = Qo;
    sc = (1.f - 0.1f * sigmoidf_(jgate[0])) * 0.08838834764831843f;  // 1/sqrt(128)
  } else if (sel == 1) {
    A = Xb; B = Wkb; bias = bk; C = Ko;
  } else {
    A = Wvb; B = Xb; bias = bv; C = Vto; brow = true;
  }
  gemm128<false, 128>(A, B, bias, brow, sc, C, mt, nt, Asm, Bsm);
}

// ---------------------------------------------------------------------------
// Output projection: out = Ab Wo^T + bo  (fp32 out).  128x64 tiles ->
// grid (32,16) = 512 blocks = 2/CU.
// ---------------------------------------------------------------------------
__global__ __launch_bounds__(256, 2) void outproj_kernel(const __bf16* __restrict__ Ab,
                                                         const __bf16* __restrict__ Wob,
                                                         const float* __restrict__ bo,
                                                         float* __restrict__ Cout) {
  __shared__ __bf16 Asm[128 * 64];
  __shared__ __bf16 Bsm[64 * 64];
  gemm128<true, 64>(Ab, Wob, bo, false, 1.f, Cout, blockIdx.y, blockIdx.x, Asm, Bsm);
}

// ---------------------------------------------------------------------------
// Flash attention. grid (16 qtiles, 16 heads), 512 threads = 8 waves.
// R12 = R11 resubmission (container-level infra failure; OOB / LDS-budget /
// swizzle / barrier audits all clean -- R3 precedent).
// KVBLK 64 -> 128 (one barrier per 128 keys): R10 counters show
// latency/barrier-bound (MfmaUtil 16%, VALU 33%, HBM 11%); 128-key tiles
// HALVE the barrier/drain count (32->16), butterfly passes, and al/oacc
// rescales at identical MFMA count and occupancy (LDS 146 KiB < 160, still
// 1 block/CU).  Fragile parts untouched: Ps stride-72 wave-private
// (two 64-key halves, byte-identical pattern), K/V source-swizzle identical,
// no setprio/defer.
// ---------------------------------------------------------------------------
__global__ __launch_bounds__(512) void attn_kernel(const __bf16* __restrict__ Q,
                                                   const __bf16* __restrict__ Kg,
                                                   const __bf16* __restrict__ VT,
                                                   const float* __restrict__ ogate,
                                                   __bf16* __restrict__ O) {
  __shared__ __bf16 Ks[2][4 * 128 * 32];  // 2 x 32 KiB, layout [c][key(128)][32]
  __shared__ __bf16 Vs[2][4 * 128 * 32];  // 2 x 32 KiB, layout [cc(4)][d(128)][32]
  __shared__ __bf16 Ps[8 * 16 * 72];      // 18 KiB, padded stride 72 (per-half reuse)
  const int t = threadIdx.x, lane = t & 63, w = t >> 6;
  const int h = blockIdx.y, qt = blockIdx.x;
  const float beta = sigmoidf_(ogate[0]) * 0.05f / 2048.0f;

  // per-lane swizzled 8-elem slot offset for K/V reads:
  // slot' = (lane>>4) ^ (row bits 1..2), row = *16 + (lane&15)
  const int rs8 = (((lane >> 4) ^ ((lane >> 1) & 3)) & 3) * 8;

  const int qrow = qt * 128 + w * 16 + (lane & 15);
  bf16x8 qf[4];
#pragma unroll
  for (int c = 0; c < 4; ++c)
    qf[c] = *(const bf16x8*)(Q + (size_t)qrow * DIM + h * 128 + c * 32 + (lane >> 4) * 8);

  f32x4 oacc[8] = {};
  float m_r[4], l_r[4];
#pragma unroll
  for (int r = 0; r < 4; ++r) { m_r[r] = -1e30f; l_r[r] = 0.f; }

  // stage a 128-key K/V tile into buffer buf (LDS dest linear, source
  // pre-swizzled; XOR touches byte bits 4-5 only -> affects ke alone).
  // 512 thr x 16 B = 8 KiB per i; K and V are 32 KiB each -> i < 4.
  auto stage = [&](int buf, int kt) {
#pragma unroll
    for (int i = 0; i < 4; ++i) {
      const int o = i * 8192 + t * 16;            // linear LDS byte offset, 0..32767
      const int oz = o ^ (((o >> 7) & 3) << 4);   // swizzled (row bits 1-2 into slot)
      const int ke = (oz & 63) >> 1;              // element offset in 32-wide row
      const int row = (o & 8191) >> 6;            // key (K) / d (V), 0..127; plane = i
      __builtin_amdgcn_global_load_lds(
          (gas_t)(Kg + (size_t)(kt + row) * DIM + h * 128 + i * 32 + ke),
          (las_t)(&Ks[buf][0] + (o >> 1)), 16, 0, 0);
      __builtin_amdgcn_global_load_lds(
          (gas_t)(VT + (size_t)(h * 128 + row) * DIM + kt + i * 32 + ke),
          (las_t)(&Vs[buf][0] + (o >> 1)), 16, 0, 0);
    }
  };

  stage(0, 0);
  int p = 0;
  for (int kt = 0; kt < 2048; kt += 128) {
    __syncthreads();  // buf[p] staged (vmcnt drained here); buf[p^1] reads from t-1 done
    if (kt + 128 < 2048) stage(p ^ 1, kt + 128);  // prefetch; drains at NEXT barrier

    // QK^T: sc[j] = 16q x 16key block j (8 blocks = 128 keys)
    f32x4 sc[8];
#pragma unroll
    for (int j = 0; j < 8; ++j) {
      f32x4 a = {};
#pragma unroll
      for (int c = 0; c < 4; ++c) {
        bf16x8 kf = *(const bf16x8*)(&Ks[p][0] + c * 4096 + (j * 16 + (lane & 15)) * 32 + rs8);
        a = __builtin_amdgcn_mfma_f32_16x16x32_bf16(qf[c], kf, a, 0, 0, 0);
      }
      sc[j] = a;
    }
    // per-key position bias
#pragma unroll
    for (int j = 0; j < 8; ++j) {
      const float pb = beta * (float)(kt + j * 16 + (lane & 15));
#pragma unroll
      for (int r = 0; r < 4; ++r) sc[j][r] += pb;
    }
    // row max over 128 keys: regs then one 16-lane butterfly
    float rmax[4];
#pragma unroll
    for (int r = 0; r < 4; ++r) {
      rmax[r] = fmaxf(fmaxf(sc[0][r], sc[1][r]), fmaxf(sc[2][r], sc[3][r]));
      rmax[r] = fmaxf(rmax[r], fmaxf(fmaxf(sc[4][r], sc[5][r]), fmaxf(sc[6][r], sc[7][r])));
    }
#pragma unroll
    for (int msk = 1; msk < 16; msk <<= 1)
#pragma unroll
      for (int r = 0; r < 4; ++r) rmax[r] = fmaxf(rmax[r], __shfl_xor(rmax[r], msk, 64));

    float al[4];
#pragma unroll
    for (int r = 0; r < 4; ++r) {
      const float mn = fmaxf(m_r[r], rmax[r]);
      al[r] = __expf(m_r[r] - mn);
      m_r[r] = mn;
    }
#pragma unroll
    for (int j = 0; j < 8; ++j)
#pragma unroll
      for (int r = 0; r < 4; ++r) sc[j][r] = __expf(sc[j][r] - m_r[r]);

    float rs[4];
#pragma unroll
    for (int r = 0; r < 4; ++r)
      rs[r] = ((sc[0][r] + sc[1][r]) + (sc[2][r] + sc[3][r])) +
              ((sc[4][r] + sc[5][r]) + (sc[6][r] + sc[7][r]));
#pragma unroll
    for (int msk = 1; msk < 16; msk <<= 1)
#pragma unroll
      for (int r = 0; r < 4; ++r) rs[r] += __shfl_xor(rs[r], msk, 64);
#pragma unroll
    for (int r = 0; r < 4; ++r) l_r[r] = l_r[r] * al[r] + rs[r];
#pragma unroll
    for (int d = 0; d < 8; ++d)
#pragma unroll
      for (int r = 0; r < 4; ++r) oacc[d][r] *= al[r];

    // Two 64-key halves through the wave-private Ps (stride 72, same pattern
    // as the measured-best R8 body).  Same-wave LDS ordering via lgkmcnt --
    // the half-1 writes cannot pass the half-0 pa reads (in-order DS).
#pragma unroll
    for (int half = 0; half < 2; ++half) {
      __bf16* pw = Ps + w * 1152;
#pragma unroll
      for (int jj = 0; jj < 4; ++jj)
#pragma unroll
        for (int r = 0; r < 4; ++r)
          pw[((lane >> 4) * 4 + r) * 72 + jj * 16 + (lane & 15)] = (__bf16)sc[half * 4 + jj][r];
#pragma unroll
      for (int cc2 = 0; cc2 < 2; ++cc2) {
        const int cc = half * 2 + cc2;
        bf16x8 pa = *(const bf16x8*)(Ps + w * 1152 + (lane & 15) * 72 + cc2 * 32 + (lane >> 4) * 8);
#pragma unroll
        for (int d = 0; d < 8; ++d) {
          bf16x8 vf = *(const bf16x8*)(&Vs[p][0] + cc * 4096 + (d * 16 + (lane & 15)) * 32 + rs8);
          oacc[d] = __builtin_amdgcn_mfma_f32_16x16x32_bf16(pa, vf, oacc[d], 0, 0, 0);
        }
      }
    }
    p ^= 1;
  }

  // epilogue: normalize and store bf16 attention output [S][2048]
#pragma unroll
  for (int d = 0; d < 8; ++d)
#pragma unroll
    for (int r = 0; r < 4; ++r) {
      const int row = qt * 128 + w * 16 + (lane >> 4) * 4 + r;
      const int col = h * 128 + d * 16 + (lane & 15);
      O[(size_t)row * DIM + col] = (__bf16)(oacc[d][r] / l_r[r]);
    }
}

// ---------------------------------------------------------------------------
extern "C" void kernel_launch(void* const* d_in, const int* in_sizes, int n_in,
                              void* d_out, int out_size, void* d_ws, size_t ws_size,
                              hipStream_t stream) {
  const float* X  = (const float*)d_in[0];
  const float* Wq = (const float*)d_in[1];
  const float* bq = (const float*)d_in[2];
  const float* Wk = (const float*)d_in[3];
  const float* bk = (const float*)d_in[4];
  const float* Wv = (const float*)d_in[5];
  const float* bv = (const float*)d_in[6];
  const float* Wo = (const float*)d_in[7];
  const float* bo = (const float*)d_in[8];
  // gates: truth(9), balance(10), order(11), justice(12), harmony(13)
  const float* order_g   = (const float*)d_in[11];
  const float* justice_g = (const float*)d_in[12];

  __bf16* wsb = (__bf16*)d_ws;
  __bf16* Xb  = wsb + 0 * MAT;
  __bf16* Wqb = wsb + 1 * MAT;
  __bf16* Wkb = wsb + 2 * MAT;
  __bf16* Wvb = wsb + 3 * MAT;
  __bf16* Wob = wsb + 4 * MAT;
  __bf16* Qb  = wsb + 5 * MAT;
  __bf16* Kb  = wsb + 6 * MAT;
  __bf16* VTb = wsb + 7 * MAT;
  __bf16* Ab  = Xb;  // alias: X is dead after qkv_kernel (keeps ws use at 64 MB)

  cvt_kernel<<<dim3(4096, 5), 256, 0, stream>>>(X, Wq, Wk, Wv, Wo, wsb);
  qkv_kernel<<<dim3(48, 16), 256, 0, stream>>>(Xb, Wqb, Wkb, Wvb, bq, bk, bv, justice_g,
                                               Qb, Kb, VTb);
  attn_kernel<<<dim3(16, 16), 512, 0, stream>>>(Qb, Kb, VTb, order_g, Ab);
  outproj_kernel<<<dim3(32, 16), 256, 0, stream>>>(Ab, Wob, bo, (float*)d_out);
}

// Round 13
// 278.454 us; speedup vs baseline: 1.2961x; 1.0447x over previous
//
#include <hip/hip_runtime.h>

typedef __bf16 bf16x8 __attribute__((ext_vector_type(8)));
typedef __bf16 bf16x4 __attribute__((ext_vector_type(4)));
typedef float f32x4 __attribute__((ext_vector_type(4)));

typedef const __attribute__((address_space(1))) void* gas_t;
typedef __attribute__((address_space(3))) void* las_t;

static constexpr int DIM = 2048;
static constexpr size_t MAT = (size_t)DIM * DIM;  // 4194304 elements

__device__ __forceinline__ float sigmoidf_(float x) { return 1.f / (1.f + __expf(-x)); }

// ---------------------------------------------------------------------------
// fp32 -> bf16 conversion for X, Wq, Wk, Wv, Wo  (grid: (4096, 5), 256 thr)
// ---------------------------------------------------------------------------
__global__ void cvt_kernel(const float* __restrict__ x, const float* __restrict__ wq,
                           const float* __restrict__ wk, const float* __restrict__ wv,
                           const float* __restrict__ wo, __bf16* __restrict__ dst) {
  const float* s;
  switch (blockIdx.y) {
    case 0: s = x; break;
    case 1: s = wq; break;
    case 2: s = wk; break;
    case 3: s = wv; break;
    default: s = wo; break;
  }
  __bf16* d = dst + (size_t)blockIdx.y * MAT;
  size_t i = ((size_t)blockIdx.x * 256 + threadIdx.x) * 4;
  float4 v = *(const float4*)(s + i);
  bf16x4 ov;
  ov[0] = (__bf16)v.x; ov[1] = (__bf16)v.y; ov[2] = (__bf16)v.z; ov[3] = (__bf16)v.w;
  *(bf16x4*)(d + i) = ov;
}

// ---------------------------------------------------------------------------
// 128xBN GEMM body, BK-templated + row-XOR LDS swizzle: C = A*B^T (+bias).
// 2-barrier single-buffer skeleton (measured best R2/R5/R7).
//  * Swizzle: both-sides involution byte^=(row&7)<<4 (pre-swizzled global
//    source, XOR'd read slot) -> every 16-lane ds_read_b128 phase covers all
//    8 sixteen-byte quads twice = 2-way = free (m136).  Works for BK=64
//    (128-B rows) and BK=128 (256-B rows: row*256 = 0 mod bank cycle, so the
//    row-bits-into-slot XOR is still the full spreader).
//  * BK choice per kernel is an occupancy trade (R5/R12 lesson):
//      qkv: BK=64, LDS 32 KiB -> 3 blocks/CU (BK=128 would cut to 2: -20us).
//      outproj: BK=128, LDS 48 KiB -> grid 2/CU unchanged; barrier/drain
//      count halves 32->16 at zero occupancy cost (the R12 attn lever).
// ---------------------------------------------------------------------------
template <bool F32OUT, int BN, int BK>
__device__ __forceinline__ void gemm128(const __bf16* __restrict__ A, const __bf16* __restrict__ B,
                                        const float* __restrict__ bias, bool bias_row, float scale,
                                        void* __restrict__ Cout, int mtile, int ntile,
                                        __bf16* Asm, __bf16* Bsm) {
  constexpr int NJ = BN / 32;             // B-fragment blocks per wave
  constexpr int RSH = (BK == 64) ? 7 : 8; // log2(row bytes)
  constexpr int KM = BK * 2 - 1;          // byte mask within a row
  const int t = threadIdx.x, lane = t & 63, w = t >> 6;
  const int wrow = (w >> 1) * 64, wcol = (w & 1) * (BN / 2);
  const int rbase = mtile * 128, cbase = ntile * BN;
  const int rx8 = (lane & 7) << 3;  // element-index XOR: row&7 into slot bits 3..5
  f32x4 acc[4][NJ] = {};

  for (int k0 = 0; k0 < DIM; k0 += BK) {
    __syncthreads();  // previous iteration's LDS reads complete
#pragma unroll
    for (int i = 0; i < BK / 16; ++i) {  // A tile: 128 rows x BK k x 2B
      const int o = i * 4096 + t * 16;                  // linear LDS byte offset
      const int r = o >> RSH;                           // row 0..127
      const int ke = ((o ^ ((r & 7) << 4)) & KM) >> 1;  // logical k elem (mult of 8)
      __builtin_amdgcn_global_load_lds((gas_t)(A + (size_t)(rbase + r) * DIM + k0 + ke),
                                       (las_t)(Asm + (o >> 1)), 16, 0, 0);
    }
#pragma unroll
    for (int i = 0; i < (BN * BK) / 2048; ++i) {  // B tile: BN rows x BK k
      const int o = i * 4096 + t * 16;
      const int r = o >> RSH;  // row 0..BN-1
      const int ke = ((o ^ ((r & 7) << 4)) & KM) >> 1;
      __builtin_amdgcn_global_load_lds((gas_t)(B + (size_t)(cbase + r) * DIM + k0 + ke),
                                       (las_t)(Bsm + (o >> 1)), 16, 0, 0);
    }
    __syncthreads();  // compiler drains vmcnt before barrier

#pragma unroll
    for (int hh = 0; hh < BK / 32; ++hh) {  // K=32 halves of the BK tile
      const int kb = hh * 32 + (lane >> 4) * 8;  // logical elem offset in row
      bf16x8 af[4], bf[NJ];
#pragma unroll
      for (int i = 0; i < 4; ++i)
        af[i] = *(const bf16x8*)(Asm + (wrow + i * 16 + (lane & 15)) * BK + (kb ^ rx8));
#pragma unroll
      for (int j = 0; j < NJ; ++j)
        bf[j] = *(const bf16x8*)(Bsm + (wcol + j * 16 + (lane & 15)) * BK + (kb ^ rx8));
#pragma unroll
      for (int i = 0; i < 4; ++i)
#pragma unroll
        for (int j = 0; j < NJ; ++j)
          acc[i][j] = __builtin_amdgcn_mfma_f32_16x16x32_bf16(af[i], bf[j], acc[i][j], 0, 0, 0);
    }
  }

  // epilogue: C/D layout col = lane&15, row = (lane>>4)*4 + r
#pragma unroll
  for (int i = 0; i < 4; ++i)
#pragma unroll
    for (int j = 0; j < NJ; ++j)
#pragma unroll
      for (int r = 0; r < 4; ++r) {
        const int row = rbase + wrow + i * 16 + (lane >> 4) * 4 + r;
        const int col = cbase + wcol + j * 16 + (lane & 15);
        float v = acc[i][j][r] + (bias_row ? bias[row] : bias[col]);
        v *= scale;
        if (F32OUT)
          ((float*)Cout)[(size_t)row * DIM + col] = v;
        else
          ((__bf16*)Cout)[(size_t)row * DIM + col] = (__bf16)v;
      }
}

// ---------------------------------------------------------------------------
// Fused QKV projections. grid (48,16): sel = x>>4 picks Q / K / V^T.
// BK=64: LDS 32 KiB keeps 3 blocks/CU (BK=128 would cut to 2 -- R5's -20us).
// ---------------------------------------------------------------------------
__global__ __launch_bounds__(256, 2) void qkv_kernel(
    const __bf16* __restrict__ Xb, const __bf16* __restrict__ Wqb, const __bf16* __restrict__ Wkb,
    const __bf16* __restrict__ Wvb, const float* __restrict__ bq, const float* __restrict__ bk,
    const float* __restrict__ bv, const float* __restrict__ jgate, __bf16* __restrict__ Qo,
    __bf16* __restrict__ Ko, __bf16* __restrict__ Vto) {
  __shared__ __bf16 Asm[128 * 64];
  __shared__ __bf16 Bsm[128 * 64];
  const int sel = blockIdx.x >> 4, nt = blockIdx.x & 15, mt = blockIdx.y;
  const __bf16 *A, *B;
  const float* bias;
  __bf16* C;
  bool brow = false;
  float sc = 1.f;
  if (sel == 0) {
    A = Xb; B = Wqb; bias = bq; C = Qo;
    sc = (1.f - 0.1f * sigmoidf_(jgate[0])) * 0.08838834764831843f;  // 1/sqrt(128)
  } else if (sel == 1) {
    A = Xb; B = Wkb; bias = bk; C = Ko;
  } else {
    A = Wvb; B = Xb; bias = bv; C = Vto; brow = true;
  }
  gemm128<false, 128, 64>(A, B, bias, brow, sc, C, mt, nt, Asm, Bsm);
}

// ---------------------------------------------------------------------------
// Output projection: out = Ab Wo^T + bo  (fp32 out).  128x64 tiles,
// grid (32,16) = 512 blocks = 2/CU.  BK=128: LDS 48 KiB still fits 2
// blocks/CU, so barrier/drain count halves (32->16) at zero occupancy cost
// -- the R12 attn lever applied to the GEMM side.
// ---------------------------------------------------------------------------
__global__ __launch_bounds__(256, 2) void outproj_kernel(const __bf16* __restrict__ Ab,
                                                         const __bf16* __restrict__ Wob,
                                                         const float* __restrict__ bo,
                                                         float* __restrict__ Cout) {
  __shared__ __bf16 Asm[128 * 128];
  __shared__ __bf16 Bsm[64 * 128];
  gemm128<true, 64, 128>(Ab, Wob, bo, false, 1.f, Cout, blockIdx.y, blockIdx.x, Asm, Bsm);
}

// ---------------------------------------------------------------------------
// Flash attention. grid (16 qtiles, 16 heads), 512 threads = 8 waves.
// EXACT R12 body (measured 74.6 us): KVBLK=128, one barrier per 128 keys,
// Ps stride-72 wave-private, K/V source-swizzle, no setprio/defer.
// ---------------------------------------------------------------------------
__global__ __launch_bounds__(512) void attn_kernel(const __bf16* __restrict__ Q,
                                                   const __bf16* __restrict__ Kg,
                                                   const __bf16* __restrict__ VT,
                                                   const float* __restrict__ ogate,
                                                   __bf16* __restrict__ O) {
  __shared__ __bf16 Ks[2][4 * 128 * 32];  // 2 x 32 KiB, layout [c][key(128)][32]
  __shared__ __bf16 Vs[2][4 * 128 * 32];  // 2 x 32 KiB, layout [cc(4)][d(128)][32]
  __shared__ __bf16 Ps[8 * 16 * 72];      // 18 KiB, padded stride 72 (per-half reuse)
  const int t = threadIdx.x, lane = t & 63, w = t >> 6;
  const int h = blockIdx.y, qt = blockIdx.x;
  const float beta = sigmoidf_(ogate[0]) * 0.05f / 2048.0f;

  // per-lane swizzled 8-elem slot offset for K/V reads:
  // slot' = (lane>>4) ^ (row bits 1..2), row = *16 + (lane&15)
  const int rs8 = (((lane >> 4) ^ ((lane >> 1) & 3)) & 3) * 8;

  const int qrow = qt * 128 + w * 16 + (lane & 15);
  bf16x8 qf[4];
#pragma unroll
  for (int c = 0; c < 4; ++c)
    qf[c] = *(const bf16x8*)(Q + (size_t)qrow * DIM + h * 128 + c * 32 + (lane >> 4) * 8);

  f32x4 oacc[8] = {};
  float m_r[4], l_r[4];
#pragma unroll
  for (int r = 0; r < 4; ++r) { m_r[r] = -1e30f; l_r[r] = 0.f; }

  // stage a 128-key K/V tile into buffer buf (LDS dest linear, source
  // pre-swizzled; XOR touches byte bits 4-5 only -> affects ke alone).
  auto stage = [&](int buf, int kt) {
#pragma unroll
    for (int i = 0; i < 4; ++i) {
      const int o = i * 8192 + t * 16;            // linear LDS byte offset, 0..32767
      const int oz = o ^ (((o >> 7) & 3) << 4);   // swizzled (row bits 1-2 into slot)
      const int ke = (oz & 63) >> 1;              // element offset in 32-wide row
      const int row = (o & 8191) >> 6;            // key (K) / d (V), 0..127; plane = i
      __builtin_amdgcn_global_load_lds(
          (gas_t)(Kg + (size_t)(kt + row) * DIM + h * 128 + i * 32 + ke),
          (las_t)(&Ks[buf][0] + (o >> 1)), 16, 0, 0);
      __builtin_amdgcn_global_load_lds(
          (gas_t)(VT + (size_t)(h * 128 + row) * DIM + kt + i * 32 + ke),
          (las_t)(&Vs[buf][0] + (o >> 1)), 16, 0, 0);
    }
  };

  stage(0, 0);
  int p = 0;
  for (int kt = 0; kt < 2048; kt += 128) {
    __syncthreads();  // buf[p] staged (vmcnt drained here); buf[p^1] reads from t-1 done
    if (kt + 128 < 2048) stage(p ^ 1, kt + 128);  // prefetch; drains at NEXT barrier

    // QK^T: sc[j] = 16q x 16key block j (8 blocks = 128 keys)
    f32x4 sc[8];
#pragma unroll
    for (int j = 0; j < 8; ++j) {
      f32x4 a = {};
#pragma unroll
      for (int c = 0; c < 4; ++c) {
        bf16x8 kf = *(const bf16x8*)(&Ks[p][0] + c * 4096 + (j * 16 + (lane & 15)) * 32 + rs8);
        a = __builtin_amdgcn_mfma_f32_16x16x32_bf16(qf[c], kf, a, 0, 0, 0);
      }
      sc[j] = a;
    }
    // per-key position bias
#pragma unroll
    for (int j = 0; j < 8; ++j) {
      const float pb = beta * (float)(kt + j * 16 + (lane & 15));
#pragma unroll
      for (int r = 0; r < 4; ++r) sc[j][r] += pb;
    }
    // row max over 128 keys: regs then one 16-lane butterfly
    float rmax[4];
#pragma unroll
    for (int r = 0; r < 4; ++r) {
      rmax[r] = fmaxf(fmaxf(sc[0][r], sc[1][r]), fmaxf(sc[2][r], sc[3][r]));
      rmax[r] = fmaxf(rmax[r], fmaxf(fmaxf(sc[4][r], sc[5][r]), fmaxf(sc[6][r], sc[7][r])));
    }
#pragma unroll
    for (int msk = 1; msk < 16; msk <<= 1)
#pragma unroll
      for (int r = 0; r < 4; ++r) rmax[r] = fmaxf(rmax[r], __shfl_xor(rmax[r], msk, 64));

    float al[4];
#pragma unroll
    for (int r = 0; r < 4; ++r) {
      const float mn = fmaxf(m_r[r], rmax[r]);
      al[r] = __expf(m_r[r] - mn);
      m_r[r] = mn;
    }
#pragma unroll
    for (int j = 0; j < 8; ++j)
#pragma unroll
      for (int r = 0; r < 4; ++r) sc[j][r] = __expf(sc[j][r] - m_r[r]);

    float rs[4];
#pragma unroll
    for (int r = 0; r < 4; ++r)
      rs[r] = ((sc[0][r] + sc[1][r]) + (sc[2][r] + sc[3][r])) +
              ((sc[4][r] + sc[5][r]) + (sc[6][r] + sc[7][r]));
#pragma unroll
    for (int msk = 1; msk < 16; msk <<= 1)
#pragma unroll
      for (int r = 0; r < 4; ++r) rs[r] += __shfl_xor(rs[r], msk, 64);
#pragma unroll
    for (int r = 0; r < 4; ++r) l_r[r] = l_r[r] * al[r] + rs[r];
#pragma unroll
    for (int d = 0; d < 8; ++d)
#pragma unroll
      for (int r = 0; r < 4; ++r) oacc[d][r] *= al[r];

    // Two 64-key halves through the wave-private Ps (stride 72, same pattern
    // as the measured-best R8 body).  Same-wave LDS ordering via lgkmcnt --
    // the half-1 writes cannot pass the half-0 pa reads (in-order DS).
#pragma unroll
    for (int half = 0; half < 2; ++half) {
      __bf16* pw = Ps + w * 1152;
#pragma unroll
      for (int jj = 0; jj < 4; ++jj)
#pragma unroll
        for (int r = 0; r < 4; ++r)
          pw[((lane >> 4) * 4 + r) * 72 + jj * 16 + (lane & 15)] = (__bf16)sc[half * 4 + jj][r];
#pragma unroll
      for (int cc2 = 0; cc2 < 2; ++cc2) {
        const int cc = half * 2 + cc2;
        bf16x8 pa = *(const bf16x8*)(Ps + w * 1152 + (lane & 15) * 72 + cc2 * 32 + (lane >> 4) * 8);
#pragma unroll
        for (int d = 0; d < 8; ++d) {
          bf16x8 vf = *(const bf16x8*)(&Vs[p][0] + cc * 4096 + (d * 16 + (lane & 15)) * 32 + rs8);
          oacc[d] = __builtin_amdgcn_mfma_f32_16x16x32_bf16(pa, vf, oacc[d], 0, 0, 0);
        }
      }
    }
    p ^= 1;
  }

  // epilogue: normalize and store bf16 attention output [S][2048]
#pragma unroll
  for (int d = 0; d < 8; ++d)
#pragma unroll
    for (int r = 0; r < 4; ++r) {
      const int row = qt * 128 + w * 16 + (lane >> 4) * 4 + r;
      const int col = h * 128 + d * 16 + (lane & 15);
      O[(size_t)row * DIM + col] = (__bf16)(oacc[d][r] / l_r[r]);
    }
}

// ---------------------------------------------------------------------------
extern "C" void kernel_launch(void* const* d_in, const int* in_sizes, int n_in,
                              void* d_out, int out_size, void* d_ws, size_t ws_size,
                              hipStream_t stream) {
  const float* X  = (const float*)d_in[0];
  const float* Wq = (const float*)d_in[1];
  const float* bq = (const float*)d_in[2];
  const float* Wk = (const float*)d_in[3];
  const float* bk = (const float*)d_in[4];
  const float* Wv = (const float*)d_in[5];
  const float* bv = (const float*)d_in[6];
  const float* Wo = (const float*)d_in[7];
  const float* bo = (const float*)d_in[8];
  // gates: truth(9), balance(10), order(11), justice(12), harmony(13)
  const float* order_g   = (const float*)d_in[11];
  const float* justice_g = (const float*)d_in[12];

  __bf16* wsb = (__bf16*)d_ws;
  __bf16* Xb  = wsb + 0 * MAT;
  __bf16* Wqb = wsb + 1 * MAT;
  __bf16* Wkb = wsb + 2 * MAT;
  __bf16* Wvb = wsb + 3 * MAT;
  __bf16* Wob = wsb + 4 * MAT;
  __bf16* Qb  = wsb + 5 * MAT;
  __bf16* Kb  = wsb + 6 * MAT;
  __bf16* VTb = wsb + 7 * MAT;
  __bf16* Ab  = Xb;  // alias: X is dead after qkv_kernel (keeps ws use at 64 MB)

  cvt_kernel<<<dim3(4096, 5), 256, 0, stream>>>(X, Wq, Wk, Wv, Wo, wsb);
  qkv_kernel<<<dim3(48, 16), 256, 0, stream>>>(Xb, Wqb, Wkb, Wvb, bq, bk, bv, justice_g,
                                               Qb, Kb, VTb);
  attn_kernel<<<dim3(16, 16), 512, 0, stream>>>(Qb, Kb, VTb, order_g, Ab);
  outproj_kernel<<<dim3(32, 16), 256, 0, stream>>>(Ab, Wob, bo, (float*)d_out);
}